// Round 6
// baseline (486.230 us; speedup 1.0000x reference)
//
#include <hip/hip_runtime.h>

#define N_NODES 100000
#define N_EDGES 1250000
#define N_GRAPHS 64
#define F_INN 29
#define HD 64
#define NT 6
#define GT 4
#define NLAYERS 4
#define RECS_CAP 3000000  // >= E + 15*N worst-case padded size

#define RL(x, l) __int_as_float(__builtin_amdgcn_readlane(__float_as_int(x), l))

// ---------------- CSR construction ----------------

__global__ void count_edges(const int* __restrict__ col, int* __restrict__ cnt, int E) {
    int e = blockIdx.x * blockDim.x + threadIdx.x;
    if (e < E) atomicAdd(&cnt[col[e]], 1);
}

// dis = (deg+self)^-1/2 ; cnt16 = degree padded to multiple of 16
__global__ void compute_dis(const int* __restrict__ cnt, float* __restrict__ dis,
                            int* __restrict__ cnt16, int n) {
    int i = blockIdx.x * blockDim.x + threadIdx.x;
    if (i < n) {
        int c = cnt[i];
        dis[i] = rsqrtf((float)(c + 1));
        cnt16[i] = (c + 15) & ~15;
    }
}

// exclusive scan, 3-kernel hierarchy. scan1: 1024 elems/block (4/thread, block=256)
__global__ void scan1(const int* __restrict__ in, int* __restrict__ out,
                      int* __restrict__ bsums, int n) {
    __shared__ int wsum[4];
    int tid = threadIdx.x;
    int base = blockIdx.x * 1024 + tid * 4;
    int v0 = (base + 0 < n) ? in[base + 0] : 0;
    int v1 = (base + 1 < n) ? in[base + 1] : 0;
    int v2 = (base + 2 < n) ? in[base + 2] : 0;
    int v3 = (base + 3 < n) ? in[base + 3] : 0;
    int tsum = v0 + v1 + v2 + v3;
    int incl = tsum;
    int lane = tid & 63;
    #pragma unroll
    for (int off = 1; off < 64; off <<= 1) {
        int t = __shfl_up(incl, (unsigned)off, 64);
        if (lane >= off) incl += t;
    }
    if (lane == 63) wsum[tid >> 6] = incl;
    __syncthreads();
    int woff = 0;
    for (int w = 0; w < (tid >> 6); ++w) woff += wsum[w];
    int run = woff + incl - tsum;  // exclusive prefix of this thread's first elem
    if (base + 0 < n) out[base + 0] = run; run += v0;
    if (base + 1 < n) out[base + 1] = run; run += v1;
    if (base + 2 < n) out[base + 2] = run; run += v2;
    if (base + 3 < n) out[base + 3] = run;
    if (tid == 255) bsums[blockIdx.x] = woff + incl;  // block total
}

__global__ void scan2(int* __restrict__ bsums, int nb) {
    __shared__ int s[256];
    int tid = threadIdx.x;
    int v = (tid < nb) ? bsums[tid] : 0;
    s[tid] = v;
    __syncthreads();
    #pragma unroll
    for (int off = 1; off < 256; off <<= 1) {
        int t = (tid >= off) ? s[tid - off] : 0;
        __syncthreads();
        s[tid] += t;
        __syncthreads();
    }
    if (tid < nb) bsums[tid] = s[tid] - v;  // exclusive, in place
}

__global__ void scan3(int* __restrict__ out, const int* __restrict__ bsums, int n) {
    int i = blockIdx.x * blockDim.x + threadIdx.x;
    if (i < n) out[i] += bsums[i >> 10];
}

// packed edge record: {src index (bit-cast), dis[src]}; pad slots stay {0, 0.0}
__global__ void fill_kernel(const int* __restrict__ row, const int* __restrict__ col,
                            const int* __restrict__ offs, int* __restrict__ cursor,
                            float2* __restrict__ recs,
                            const float* __restrict__ dis, int E) {
    int e = blockIdx.x * blockDim.x + threadIdx.x;
    if (e >= E) return;
    int r = row[e], c = col[e];
    int pos = offs[c] + atomicAdd(&cursor[c], 1);
    recs[pos] = make_float2(__int_as_float(r), dis[r]);
}

// graph boundary offsets from sorted batch; start has G+1 entries
__global__ void graph_bounds(const int* __restrict__ batch, int* __restrict__ start, int n) {
    int i = blockIdx.x * blockDim.x + threadIdx.x;
    if (i >= n) return;
    int b = batch[i];
    if (i == 0) {
        for (int g = 0; g <= b; ++g) start[g] = 0;
    } else {
        int pb = batch[i - 1];
        if (pb != b) for (int g = pb + 1; g <= b; ++g) start[g] = i;
    }
    if (i == n - 1) {
        for (int g = b + 1; g <= N_GRAPHS; ++g) start[g] = n;
    }
}

// ---------------- dense layers ----------------

// h = relu(x @ encW + encb), x: [n,29], W: [29,64]
__global__ void encoder_kernel(const float* __restrict__ x, const float* __restrict__ W,
                               const float* __restrict__ b, float* __restrict__ h, int n) {
    __shared__ float Ws[F_INN * HD];
    __shared__ float bs[HD];
    __shared__ float xs[16 * F_INN];
    int tid = threadIdx.x;
    for (int i = tid; i < F_INN * HD; i += 256) Ws[i] = W[i];
    if (tid < HD) bs[tid] = b[tid];
    int n0 = blockIdx.x * 16;
    for (int i = tid; i < 16 * F_INN; i += 256) {
        int nn = n0 + i / F_INN;
        xs[i] = (nn < n) ? x[(size_t)nn * F_INN + (i % F_INN)] : 0.f;
    }
    __syncthreads();
    #pragma unroll
    for (int it = 0; it < 4; ++it) {
        int l = it * 4 + (tid >> 6);
        int j = tid & 63;
        int nn = n0 + l;
        if (nn < n) {
            float a = bs[j];
            #pragma unroll
            for (int k = 0; k < F_INN; ++k) a = fmaf(xs[l * F_INN + k], Ws[k * HD + j], a);
            h[(size_t)nn * HD + j] = fmaxf(a, 0.f);
        }
    }
}

// Fused GCN layer. Block = 256 threads = 4 waves; each wave owns 4 nodes.
// Gather (per node): padded edge list, 4 edges per quarter-wave per iter,
// recs as 2x float4 broadcast, butterfly reduce over quarters.
// Matvec: joint over the wave's 4 nodes — each Ws LDS read feeds 4 FMAs;
// agg broadcast via v_readlane (VALU), zero LDS traffic for acc.
__global__ void layer_kernel(const float* __restrict__ h,
                             const int* __restrict__ offs, const int* __restrict__ cnt16,
                             const float4* __restrict__ recs4,
                             const float* __restrict__ dis,
                             const float* __restrict__ W, const float* __restrict__ b,
                             float* __restrict__ hout) {
    __shared__ float Ws[HD * HD];
    __shared__ float bs[HD];
    int tid = threadIdx.x;
    for (int i = tid; i < HD * HD; i += 256) Ws[i] = W[i];
    if (tid < HD) bs[tid] = b[tid];
    __syncthreads();
    int wave = tid >> 6;
    int lane = tid & 63;
    int j = lane;
    float bb = bs[j];
    int q = lane >> 4;        // edge subgroup 0..3
    int f = (lane & 15) * 4;  // feature offset
    int node0 = blockIdx.x * 16 + wave * 4;  // grid*16 == N exactly, no tail

    auto gather = [&](int node, float4& A, float& dn) {
        int s = offs[node];
        int e16 = s + cnt16[node];
        dn = dis[node];
        const float4 hv = *reinterpret_cast<const float4*>(&h[(size_t)node * HD + f]);
        A = make_float4(0.f, 0.f, 0.f, 0.f);
        for (int p = s; p < e16; p += 16) {
            int base = (p + 4 * q) >> 1;  // float4 index (pair of recs)
            const float4 ra = recs4[base];      // {src0,w0,src1,w1}
            const float4 rb = recs4[base + 1];  // {src2,w2,src3,w3}
            const float4 h0 = *reinterpret_cast<const float4*>(&h[(size_t)__float_as_int(ra.x) * HD + f]);
            const float4 h1 = *reinterpret_cast<const float4*>(&h[(size_t)__float_as_int(ra.z) * HD + f]);
            const float4 h2 = *reinterpret_cast<const float4*>(&h[(size_t)__float_as_int(rb.x) * HD + f]);
            const float4 h3 = *reinterpret_cast<const float4*>(&h[(size_t)__float_as_int(rb.z) * HD + f]);
            A.x = fmaf(ra.y, h0.x, A.x);
            A.y = fmaf(ra.y, h0.y, A.y);
            A.z = fmaf(ra.y, h0.z, A.z);
            A.w = fmaf(ra.y, h0.w, A.w);
            A.x = fmaf(ra.w, h1.x, A.x);
            A.y = fmaf(ra.w, h1.y, A.y);
            A.z = fmaf(ra.w, h1.z, A.z);
            A.w = fmaf(ra.w, h1.w, A.w);
            A.x = fmaf(rb.y, h2.x, A.x);
            A.y = fmaf(rb.y, h2.y, A.y);
            A.z = fmaf(rb.y, h2.z, A.z);
            A.w = fmaf(rb.y, h2.w, A.w);
            A.x = fmaf(rb.w, h3.x, A.x);
            A.y = fmaf(rb.w, h3.y, A.y);
            A.z = fmaf(rb.w, h3.z, A.z);
            A.w = fmaf(rb.w, h3.w, A.w);
        }
        // butterfly over quarters (bits 4,5): all lanes get the full row sum
        #pragma unroll
        for (int off = 16; off < 64; off <<= 1) {
            A.x += __shfl_xor(A.x, off, 64);
            A.y += __shfl_xor(A.y, off, 64);
            A.z += __shfl_xor(A.z, off, 64);
            A.w += __shfl_xor(A.w, off, 64);
        }
        // self term
        A.x = fmaf(dn, hv.x, A.x);
        A.y = fmaf(dn, hv.y, A.y);
        A.z = fmaf(dn, hv.z, A.z);
        A.w = fmaf(dn, hv.w, A.w);
    };

    float4 accA, accB, accC, accD;
    float dnA, dnB, dnC, dnD;
    gather(node0 + 0, accA, dnA);
    gather(node0 + 1, accB, dnB);
    gather(node0 + 2, accC, dnC);
    gather(node0 + 3, accD, dnD);

    // joint matvec: out_j = sum_k agg[k] * W[k][j]; agg[4kk+c] lives in lane kk comp c
    float aA0 = 0.f, aA1 = 0.f, aB0 = 0.f, aB1 = 0.f;
    float aC0 = 0.f, aC1 = 0.f, aD0 = 0.f, aD1 = 0.f;
    #pragma unroll
    for (int kk = 0; kk < 16; ++kk) {
        const float w0 = Ws[(4 * kk + 0) * HD + j];
        const float w1 = Ws[(4 * kk + 1) * HD + j];
        const float w2 = Ws[(4 * kk + 2) * HD + j];
        const float w3 = Ws[(4 * kk + 3) * HD + j];
        aA0 = fmaf(RL(accA.x, kk), w0, aA0);
        aA1 = fmaf(RL(accA.y, kk), w1, aA1);
        aA0 = fmaf(RL(accA.z, kk), w2, aA0);
        aA1 = fmaf(RL(accA.w, kk), w3, aA1);
        aB0 = fmaf(RL(accB.x, kk), w0, aB0);
        aB1 = fmaf(RL(accB.y, kk), w1, aB1);
        aB0 = fmaf(RL(accB.z, kk), w2, aB0);
        aB1 = fmaf(RL(accB.w, kk), w3, aB1);
        aC0 = fmaf(RL(accC.x, kk), w0, aC0);
        aC1 = fmaf(RL(accC.y, kk), w1, aC1);
        aC0 = fmaf(RL(accC.z, kk), w2, aC0);
        aC1 = fmaf(RL(accC.w, kk), w3, aC1);
        aD0 = fmaf(RL(accD.x, kk), w0, aD0);
        aD1 = fmaf(RL(accD.y, kk), w1, aD1);
        aD0 = fmaf(RL(accD.z, kk), w2, aD0);
        aD1 = fmaf(RL(accD.w, kk), w3, aD1);
    }
    hout[(size_t)(node0 + 0) * HD + j] = fmaxf(fmaf(dnA, aA0 + aA1, bb), 0.f);
    hout[(size_t)(node0 + 1) * HD + j] = fmaxf(fmaf(dnB, aB0 + aB1, bb), 0.f);
    hout[(size_t)(node0 + 2) * HD + j] = fmaxf(fmaf(dnC, aC0 + aC1, bb), 0.f);
    hout[(size_t)(node0 + 3) * HD + j] = fmaxf(fmaf(dnD, aD0 + aD1, bb), 0.f);
}

// pred_node = h @ nodeW + nodeb, W: [64,6]  (pure streaming, no atomics)
__global__ void node_head(const float* __restrict__ h, const float* __restrict__ W,
                          const float* __restrict__ b, float* __restrict__ out, int n) {
    __shared__ float Ws[HD * NT];
    __shared__ float bs[NT];
    __shared__ float hs[32 * 65];
    int tid = threadIdx.x;
    for (int i = tid; i < HD * NT; i += 256) Ws[i] = W[i];
    if (tid < NT) bs[tid] = b[tid];
    int n0 = blockIdx.x * 32;
    for (int i = tid; i < 32 * HD; i += 256) {
        int nn = n0 + (i >> 6);
        hs[(i >> 6) * 65 + (i & 63)] = (nn < n) ? h[(size_t)n0 * HD + i] : 0.f;
    }
    __syncthreads();
    int l = tid >> 3, t = tid & 7;
    int nn = n0 + l;
    if (nn < n && t < NT) {
        float a = bs[t];
        #pragma unroll
        for (int k = 0; k < HD; ++k) a = fmaf(hs[l * 65 + k], Ws[k * NT + t], a);
        out[(size_t)nn * NT + t] = a;
    }
}

// atomic-free pooling: 4 blocks per graph, each sums a contiguous quarter-range
__global__ void pool_kernel(const float* __restrict__ h, const int* __restrict__ start,
                            float* __restrict__ gpart) {
    __shared__ float red[4][HD];
    int g = blockIdx.x >> 2, q = blockIdx.x & 3;
    int s0 = start[g], e0 = start[g + 1];
    int len = e0 - s0;
    int qs = s0 + (len * q) / 4;
    int qe = s0 + (len * (q + 1)) / 4;
    int wave = threadIdx.x >> 6, lane = threadIdx.x & 63;
    float acc = 0.f;
    for (int r = qs + wave; r < qe; r += 4) acc += h[(size_t)r * HD + lane];
    red[wave][lane] = acc;
    __syncthreads();
    if (wave == 0)
        gpart[(size_t)blockIdx.x * HD + lane] =
            red[0][lane] + red[1][lane] + red[2][lane] + red[3][lane];
}

// gemb = sum(gpart quarters)/count; out = relu(gemb@g1W+g1b)@g2W + g2b
__global__ void global_head(const float* __restrict__ gpart, const int* __restrict__ start,
                            const float* __restrict__ g1W, const float* __restrict__ g1b,
                            const float* __restrict__ g2W, const float* __restrict__ g2b,
                            float* __restrict__ out) {
    __shared__ float rS[HD];
    int g = blockIdx.x;
    int j = threadIdx.x;  // 64
    int cnt = start[g + 1] - start[g];
    float inv = 1.f / fmaxf((float)cnt, 1.f);
    rS[j] = (gpart[(size_t)(4 * g + 0) * HD + j] + gpart[(size_t)(4 * g + 1) * HD + j] +
             gpart[(size_t)(4 * g + 2) * HD + j] + gpart[(size_t)(4 * g + 3) * HD + j]) * inv;
    __syncthreads();
    float a = g1b[j];
    #pragma unroll
    for (int k = 0; k < HD; ++k) a = fmaf(rS[k], g1W[k * HD + j], a);
    a = fmaxf(a, 0.f);
    float o0 = a * g2W[j * GT + 0];
    float o1 = a * g2W[j * GT + 1];
    float o2 = a * g2W[j * GT + 2];
    float o3 = a * g2W[j * GT + 3];
    #pragma unroll
    for (int off = 1; off < 64; off <<= 1) {
        o0 += __shfl_xor(o0, off, 64);
        o1 += __shfl_xor(o1, off, 64);
        o2 += __shfl_xor(o2, off, 64);
        o3 += __shfl_xor(o3, off, 64);
    }
    if (j == 0) {
        out[g * GT + 0] = o0 + g2b[0];
        out[g * GT + 1] = o1 + g2b[1];
        out[g * GT + 2] = o2 + g2b[2];
        out[g * GT + 3] = o3 + g2b[3];
    }
}

// ---------------- launch ----------------

extern "C" void kernel_launch(void* const* d_in, const int* in_sizes, int n_in,
                              void* d_out, int out_size, void* d_ws, size_t ws_size,
                              hipStream_t stream) {
    const float* x    = (const float*)d_in[0];
    const int*   ei   = (const int*)d_in[1];   // [2,E] flat: row=ei[0:E], col=ei[E:2E]
    const int*   batch= (const int*)d_in[2];
    const float* encW = (const float*)d_in[3];
    const float* encb = (const float*)d_in[4];
    const float* convW= (const float*)d_in[5]; // [L,64,64]
    const float* convb= (const float*)d_in[6]; // [L,64]
    const float* nodeW= (const float*)d_in[7];
    const float* nodeb= (const float*)d_in[8];
    const float* g1W  = (const float*)d_in[9];
    const float* g1b  = (const float*)d_in[10];
    const float* g2W  = (const float*)d_in[11];
    const float* g2b  = (const float*)d_in[12];
    float* out = (float*)d_out;

    const int N = N_NODES, E = N_EDGES;

    char* ws = (char*)d_ws;
    size_t off = 0;
    auto alloc = [&](size_t bytes) -> void* {
        void* p = ws + off;
        off += (bytes + 255) & ~(size_t)255;
        return p;
    };
    // zeroed region first (one memset): cnt, cursor, recs (pad slots must be 0)
    int*    cnt    = (int*)alloc((size_t)N * 4);
    int*    cursor = (int*)alloc((size_t)N * 4);
    float2* recs   = (float2*)alloc((size_t)RECS_CAP * 8);
    size_t zbytes = off;
    // rest
    int*   offs   = (int*)alloc((size_t)N * 4);
    int*   cnt16  = (int*)alloc((size_t)N * 4);
    float* dis    = (float*)alloc((size_t)N * 4);
    int*   bsums  = (int*)alloc(256 * 4);
    int*   start  = (int*)alloc((size_t)(N_GRAPHS + 1) * 4);
    float* gpart  = (float*)alloc((size_t)N_GRAPHS * 4 * HD * 4);
    float* h      = (float*)alloc((size_t)N * HD * 4);
    float* h2     = (float*)alloc((size_t)N * HD * 4);

    hipMemsetAsync(d_ws, 0, zbytes, stream);

    const int B = 256;
    // CSR build (padded to 16)
    count_edges<<<(E + B - 1) / B, B, 0, stream>>>(ei + E, cnt, E);
    compute_dis<<<(N + B - 1) / B, B, 0, stream>>>(cnt, dis, cnt16, N);
    int nb1 = (N + 1023) / 1024;
    scan1<<<nb1, 256, 0, stream>>>(cnt16, offs, bsums, N);
    scan2<<<1, 256, 0, stream>>>(bsums, nb1);
    scan3<<<(N + B - 1) / B, B, 0, stream>>>(offs, bsums, N);
    fill_kernel<<<(E + B - 1) / B, B, 0, stream>>>(ei, ei + E, offs, cursor, recs, dis, E);
    graph_bounds<<<(N + B - 1) / B, B, 0, stream>>>(batch, start, N);

    // encoder
    encoder_kernel<<<(N + 15) / 16, 256, 0, stream>>>(x, encW, encb, h, N);

    // GCN layers (fused aggregate + transform), ping-pong h <-> h2
    float* hin = h;
    float* hot = h2;
    for (int i = 0; i < NLAYERS; ++i) {
        layer_kernel<<<N / 16, 256, 0, stream>>>(hin, offs, cnt16, (const float4*)recs, dis,
                                                 convW + (size_t)i * HD * HD,
                                                 convb + (size_t)i * HD, hot);
        float* t = hin; hin = hot; hot = t;
    }

    // heads
    node_head<<<(N + 31) / 32, 256, 0, stream>>>(hin, nodeW, nodeb, out, N);
    pool_kernel<<<N_GRAPHS * 4, 256, 0, stream>>>(hin, start, gpart);
    global_head<<<N_GRAPHS, 64, 0, stream>>>(gpart, start, g1W, g1b, g2W, g2b, out + (size_t)N * NT);
}

// Round 7
// 447.262 us; speedup vs baseline: 1.0871x; 1.0871x over previous
//
#include <hip/hip_runtime.h>

#define N_NODES 100000
#define N_EDGES 1250000
#define N_GRAPHS 64
#define F_INN 29
#define HD 64
#define NT 6
#define GT 4
#define NLAYERS 4
#define RECS_CAP 3000000  // >= E + 15*N worst-case padded size

#define RL(x, l) __int_as_float(__builtin_amdgcn_readlane(__float_as_int(x), l))

// ---------------- CSR construction ----------------

// count incoming edges per node AND record each edge's rank within its dest
__global__ void count_edges(const int* __restrict__ col, int* __restrict__ cnt,
                            int* __restrict__ rank, int E) {
    int e = blockIdx.x * blockDim.x + threadIdx.x;
    if (e < E) rank[e] = atomicAdd(&cnt[col[e]], 1);
}

// dis = (deg+self)^-1/2 ; cnt16 = degree padded to multiple of 16
__global__ void compute_dis(const int* __restrict__ cnt, float* __restrict__ dis,
                            int* __restrict__ cnt16, int n) {
    int i = blockIdx.x * blockDim.x + threadIdx.x;
    if (i < n) {
        int c = cnt[i];
        dis[i] = rsqrtf((float)(c + 1));
        cnt16[i] = (c + 15) & ~15;
    }
}

// exclusive scan, 3-kernel hierarchy. scan1: 1024 elems/block (4/thread, block=256)
__global__ void scan1(const int* __restrict__ in, int* __restrict__ out,
                      int* __restrict__ bsums, int n) {
    __shared__ int wsum[4];
    int tid = threadIdx.x;
    int base = blockIdx.x * 1024 + tid * 4;
    int v0 = (base + 0 < n) ? in[base + 0] : 0;
    int v1 = (base + 1 < n) ? in[base + 1] : 0;
    int v2 = (base + 2 < n) ? in[base + 2] : 0;
    int v3 = (base + 3 < n) ? in[base + 3] : 0;
    int tsum = v0 + v1 + v2 + v3;
    int incl = tsum;
    int lane = tid & 63;
    #pragma unroll
    for (int off = 1; off < 64; off <<= 1) {
        int t = __shfl_up(incl, (unsigned)off, 64);
        if (lane >= off) incl += t;
    }
    if (lane == 63) wsum[tid >> 6] = incl;
    __syncthreads();
    int woff = 0;
    for (int w = 0; w < (tid >> 6); ++w) woff += wsum[w];
    int run = woff + incl - tsum;  // exclusive prefix of this thread's first elem
    if (base + 0 < n) out[base + 0] = run; run += v0;
    if (base + 1 < n) out[base + 1] = run; run += v1;
    if (base + 2 < n) out[base + 2] = run; run += v2;
    if (base + 3 < n) out[base + 3] = run;
    if (tid == 255) bsums[blockIdx.x] = woff + incl;  // block total
}

__global__ void scan2(int* __restrict__ bsums, int nb) {
    __shared__ int s[256];
    int tid = threadIdx.x;
    int v = (tid < nb) ? bsums[tid] : 0;
    s[tid] = v;
    __syncthreads();
    #pragma unroll
    for (int off = 1; off < 256; off <<= 1) {
        int t = (tid >= off) ? s[tid - off] : 0;
        __syncthreads();
        s[tid] += t;
        __syncthreads();
    }
    if (tid < nb) bsums[tid] = s[tid] - v;  // exclusive, in place
}

__global__ void scan3(int* __restrict__ out, const int* __restrict__ bsums, int n) {
    int i = blockIdx.x * blockDim.x + threadIdx.x;
    if (i < n) out[i] += bsums[i >> 10];
}

// srcs[pos] = src node of each edge, grouped by dest (atomic-free via rank)
__global__ void fill_kernel(const int* __restrict__ row, const int* __restrict__ col,
                            const int* __restrict__ rank, const int* __restrict__ offs,
                            int* __restrict__ srcs, int E) {
    int e = blockIdx.x * blockDim.x + threadIdx.x;
    if (e >= E) return;
    srcs[offs[col[e]] + rank[e]] = row[e];
}

// pad slots (cnt..cnt16) point at the reserved zero row N_NODES
__global__ void pad_fill(const int* __restrict__ cnt, const int* __restrict__ cnt16,
                         const int* __restrict__ offs, int* __restrict__ srcs, int n) {
    int i = blockIdx.x * blockDim.x + threadIdx.x;
    if (i >= n) return;
    int base = offs[i];
    int e0 = base + cnt[i];
    int e1 = base + cnt16[i];
    for (int p = e0; p < e1; ++p) srcs[p] = N_NODES;
}

// zero the reserved pad row of both feature buffers
__global__ void zero_pad_row(float* __restrict__ h, float* __restrict__ h2) {
    int t = threadIdx.x;
    if (t < HD) h[(size_t)N_NODES * HD + t] = 0.f;
    else if (t < 2 * HD) h2[(size_t)N_NODES * HD + (t - HD)] = 0.f;
}

// graph boundary offsets from sorted batch; start has G+1 entries
__global__ void graph_bounds(const int* __restrict__ batch, int* __restrict__ start, int n) {
    int i = blockIdx.x * blockDim.x + threadIdx.x;
    if (i >= n) return;
    int b = batch[i];
    if (i == 0) {
        for (int g = 0; g <= b; ++g) start[g] = 0;
    } else {
        int pb = batch[i - 1];
        if (pb != b) for (int g = pb + 1; g <= b; ++g) start[g] = i;
    }
    if (i == n - 1) {
        for (int g = b + 1; g <= N_GRAPHS; ++g) start[g] = n;
    }
}

// ---------------- dense layers ----------------

// ht = dis * relu(x @ encW + encb)   (scaled features H~)
__global__ void encoder_kernel(const float* __restrict__ x, const float* __restrict__ W,
                               const float* __restrict__ b, const float* __restrict__ dis,
                               float* __restrict__ ht, int n) {
    __shared__ float Ws[F_INN * HD];
    __shared__ float bs[HD];
    __shared__ float xs[16 * F_INN];
    int tid = threadIdx.x;
    for (int i = tid; i < F_INN * HD; i += 256) Ws[i] = W[i];
    if (tid < HD) bs[tid] = b[tid];
    int n0 = blockIdx.x * 16;
    for (int i = tid; i < 16 * F_INN; i += 256) {
        int nn = n0 + i / F_INN;
        xs[i] = (nn < n) ? x[(size_t)nn * F_INN + (i % F_INN)] : 0.f;
    }
    __syncthreads();
    #pragma unroll
    for (int it = 0; it < 4; ++it) {
        int l = it * 4 + (tid >> 6);
        int j = tid & 63;
        int nn = n0 + l;
        if (nn < n) {
            float a = bs[j];
            #pragma unroll
            for (int k = 0; k < F_INN; ++k) a = fmaf(xs[l * F_INN + k], Ws[k * HD + j], a);
            ht[(size_t)nn * HD + j] = dis[nn] * fmaxf(a, 0.f);
        }
    }
}

#define ROW(src) (*reinterpret_cast<const float4*>(&ht[(size_t)(src) * HD + f]))

// Fused GCN layer on scaled features: agg = sum_src H~[src] + H~[node] (no weights!).
// Block = 4 waves; wave owns 4 nodes with INTERLEAVED gathers (two-phase: issue all
// 4 index loads, then all 16 row loads, then accumulate) -> 16 rows in flight.
// Matvec joint over 4 nodes: Ws LDS read feeds 4 FMAs; agg broadcast via v_readlane.
// out = relu(dn*(agg@W)+b), optionally rescaled by dn (H~ for next layer).
__global__ void layer_kernel(const float* __restrict__ ht,
                             const int* __restrict__ offs, const int* __restrict__ cnt16,
                             const int4* __restrict__ srcs4,
                             const float* __restrict__ dis,
                             const float* __restrict__ W, const float* __restrict__ b,
                             float* __restrict__ hout, int scaleOut) {
    __shared__ float Ws[HD * HD];
    __shared__ float bs[HD];
    int tid = threadIdx.x;
    for (int i = tid; i < HD * HD; i += 256) Ws[i] = W[i];
    if (tid < HD) bs[tid] = b[tid];
    __syncthreads();
    int wave = tid >> 6;
    int lane = tid & 63;
    int j = lane;
    float bb = bs[j];
    int q = lane >> 4;        // edge subgroup 0..3
    int f = (lane & 15) * 4;  // feature offset
    int node0 = blockIdx.x * 16 + wave * 4;  // grid*16 == N exactly
    int nA = node0, nB = node0 + 1, nC = node0 + 2, nD = node0 + 3;
    int pA = offs[nA], eA = pA + cnt16[nA];
    int pB = offs[nB], eB = pB + cnt16[nB];
    int pC = offs[nC], eC = pC + cnt16[nC];
    int pD = offs[nD], eD = pD + cnt16[nD];
    float4 accA = {0.f, 0.f, 0.f, 0.f}, accB = accA, accC = accA, accD = accA;

    while ((pA < eA) | (pB < eB) | (pC < eC) | (pD < eD)) {
        bool cA = pA < eA, cB = pB < eB, cC = pC < eC, cD = pD < eD;
        int4 sA, sB, sC, sD;
        if (cA) sA = srcs4[(pA >> 2) + q];
        if (cB) sB = srcs4[(pB >> 2) + q];
        if (cC) sC = srcs4[(pC >> 2) + q];
        if (cD) sD = srcs4[(pD >> 2) + q];
        float4 rA0, rA1, rA2, rA3, rB0, rB1, rB2, rB3;
        float4 rC0, rC1, rC2, rC3, rD0, rD1, rD2, rD3;
        if (cA) { rA0 = ROW(sA.x); rA1 = ROW(sA.y); rA2 = ROW(sA.z); rA3 = ROW(sA.w); }
        if (cB) { rB0 = ROW(sB.x); rB1 = ROW(sB.y); rB2 = ROW(sB.z); rB3 = ROW(sB.w); }
        if (cC) { rC0 = ROW(sC.x); rC1 = ROW(sC.y); rC2 = ROW(sC.z); rC3 = ROW(sC.w); }
        if (cD) { rD0 = ROW(sD.x); rD1 = ROW(sD.y); rD2 = ROW(sD.z); rD3 = ROW(sD.w); }
        if (cA) {
            accA.x += (rA0.x + rA1.x) + (rA2.x + rA3.x);
            accA.y += (rA0.y + rA1.y) + (rA2.y + rA3.y);
            accA.z += (rA0.z + rA1.z) + (rA2.z + rA3.z);
            accA.w += (rA0.w + rA1.w) + (rA2.w + rA3.w);
            pA += 16;
        }
        if (cB) {
            accB.x += (rB0.x + rB1.x) + (rB2.x + rB3.x);
            accB.y += (rB0.y + rB1.y) + (rB2.y + rB3.y);
            accB.z += (rB0.z + rB1.z) + (rB2.z + rB3.z);
            accB.w += (rB0.w + rB1.w) + (rB2.w + rB3.w);
            pB += 16;
        }
        if (cC) {
            accC.x += (rC0.x + rC1.x) + (rC2.x + rC3.x);
            accC.y += (rC0.y + rC1.y) + (rC2.y + rC3.y);
            accC.z += (rC0.z + rC1.z) + (rC2.z + rC3.z);
            accC.w += (rC0.w + rC1.w) + (rC2.w + rC3.w);
            pC += 16;
        }
        if (cD) {
            accD.x += (rD0.x + rD1.x) + (rD2.x + rD3.x);
            accD.y += (rD0.y + rD1.y) + (rD2.y + rD3.y);
            accD.z += (rD0.z + rD1.z) + (rD2.z + rD3.z);
            accD.w += (rD0.w + rD1.w) + (rD2.w + rD3.w);
            pD += 16;
        }
    }
    // butterfly over quarters (bits 4,5): all lanes get the full row sums
    #pragma unroll
    for (int off = 16; off < 64; off <<= 1) {
        accA.x += __shfl_xor(accA.x, off, 64);
        accA.y += __shfl_xor(accA.y, off, 64);
        accA.z += __shfl_xor(accA.z, off, 64);
        accA.w += __shfl_xor(accA.w, off, 64);
        accB.x += __shfl_xor(accB.x, off, 64);
        accB.y += __shfl_xor(accB.y, off, 64);
        accB.z += __shfl_xor(accB.z, off, 64);
        accB.w += __shfl_xor(accB.w, off, 64);
        accC.x += __shfl_xor(accC.x, off, 64);
        accC.y += __shfl_xor(accC.y, off, 64);
        accC.z += __shfl_xor(accC.z, off, 64);
        accC.w += __shfl_xor(accC.w, off, 64);
        accD.x += __shfl_xor(accD.x, off, 64);
        accD.y += __shfl_xor(accD.y, off, 64);
        accD.z += __shfl_xor(accD.z, off, 64);
        accD.w += __shfl_xor(accD.w, off, 64);
    }
    // self terms (scaled features: just add the row)
    {
        const float4 hA = ROW(nA), hB = ROW(nB), hC = ROW(nC), hD = ROW(nD);
        accA.x += hA.x; accA.y += hA.y; accA.z += hA.z; accA.w += hA.w;
        accB.x += hB.x; accB.y += hB.y; accB.z += hB.z; accB.w += hB.w;
        accC.x += hC.x; accC.y += hC.y; accC.z += hC.z; accC.w += hC.w;
        accD.x += hD.x; accD.y += hD.y; accD.z += hD.z; accD.w += hD.w;
    }
    float dnA = dis[nA], dnB = dis[nB], dnC = dis[nC], dnD = dis[nD];
    // joint matvec: out_j = sum_k agg[k] * W[k][j]; agg[4kk+c] lives in lane kk comp c
    float aA0 = 0.f, aA1 = 0.f, aB0 = 0.f, aB1 = 0.f;
    float aC0 = 0.f, aC1 = 0.f, aD0 = 0.f, aD1 = 0.f;
    #pragma unroll
    for (int kk = 0; kk < 16; ++kk) {
        const float w0 = Ws[(4 * kk + 0) * HD + j];
        const float w1 = Ws[(4 * kk + 1) * HD + j];
        const float w2 = Ws[(4 * kk + 2) * HD + j];
        const float w3 = Ws[(4 * kk + 3) * HD + j];
        aA0 = fmaf(RL(accA.x, kk), w0, aA0);
        aA1 = fmaf(RL(accA.y, kk), w1, aA1);
        aA0 = fmaf(RL(accA.z, kk), w2, aA0);
        aA1 = fmaf(RL(accA.w, kk), w3, aA1);
        aB0 = fmaf(RL(accB.x, kk), w0, aB0);
        aB1 = fmaf(RL(accB.y, kk), w1, aB1);
        aB0 = fmaf(RL(accB.z, kk), w2, aB0);
        aB1 = fmaf(RL(accB.w, kk), w3, aB1);
        aC0 = fmaf(RL(accC.x, kk), w0, aC0);
        aC1 = fmaf(RL(accC.y, kk), w1, aC1);
        aC0 = fmaf(RL(accC.z, kk), w2, aC0);
        aC1 = fmaf(RL(accC.w, kk), w3, aC1);
        aD0 = fmaf(RL(accD.x, kk), w0, aD0);
        aD1 = fmaf(RL(accD.y, kk), w1, aD1);
        aD0 = fmaf(RL(accD.z, kk), w2, aD0);
        aD1 = fmaf(RL(accD.w, kk), w3, aD1);
    }
    float oA = fmaxf(fmaf(dnA, aA0 + aA1, bb), 0.f);
    float oB = fmaxf(fmaf(dnB, aB0 + aB1, bb), 0.f);
    float oC = fmaxf(fmaf(dnC, aC0 + aC1, bb), 0.f);
    float oD = fmaxf(fmaf(dnD, aD0 + aD1, bb), 0.f);
    if (scaleOut) { oA *= dnA; oB *= dnB; oC *= dnC; oD *= dnD; }
    hout[(size_t)nA * HD + j] = oA;
    hout[(size_t)nB * HD + j] = oB;
    hout[(size_t)nC * HD + j] = oC;
    hout[(size_t)nD * HD + j] = oD;
}

// pred_node = h @ nodeW + nodeb, W: [64,6]  (pure streaming, no atomics)
__global__ void node_head(const float* __restrict__ h, const float* __restrict__ W,
                          const float* __restrict__ b, float* __restrict__ out, int n) {
    __shared__ float Ws[HD * NT];
    __shared__ float bs[NT];
    __shared__ float hs[32 * 65];
    int tid = threadIdx.x;
    for (int i = tid; i < HD * NT; i += 256) Ws[i] = W[i];
    if (tid < NT) bs[tid] = b[tid];
    int n0 = blockIdx.x * 32;
    for (int i = tid; i < 32 * HD; i += 256) {
        int nn = n0 + (i >> 6);
        hs[(i >> 6) * 65 + (i & 63)] = (nn < n) ? h[(size_t)n0 * HD + i] : 0.f;
    }
    __syncthreads();
    int l = tid >> 3, t = tid & 7;
    int nn = n0 + l;
    if (nn < n && t < NT) {
        float a = bs[t];
        #pragma unroll
        for (int k = 0; k < HD; ++k) a = fmaf(hs[l * 65 + k], Ws[k * NT + t], a);
        out[(size_t)nn * NT + t] = a;
    }
}

// atomic-free pooling: 4 blocks per graph, each sums a contiguous quarter-range
__global__ void pool_kernel(const float* __restrict__ h, const int* __restrict__ start,
                            float* __restrict__ gpart) {
    __shared__ float red[4][HD];
    int g = blockIdx.x >> 2, q = blockIdx.x & 3;
    int s0 = start[g], e0 = start[g + 1];
    int len = e0 - s0;
    int qs = s0 + (len * q) / 4;
    int qe = s0 + (len * (q + 1)) / 4;
    int wave = threadIdx.x >> 6, lane = threadIdx.x & 63;
    float acc = 0.f;
    for (int r = qs + wave; r < qe; r += 4) acc += h[(size_t)r * HD + lane];
    red[wave][lane] = acc;
    __syncthreads();
    if (wave == 0)
        gpart[(size_t)blockIdx.x * HD + lane] =
            red[0][lane] + red[1][lane] + red[2][lane] + red[3][lane];
}

// gemb = sum(gpart quarters)/count; out = relu(gemb@g1W+g1b)@g2W + g2b
__global__ void global_head(const float* __restrict__ gpart, const int* __restrict__ start,
                            const float* __restrict__ g1W, const float* __restrict__ g1b,
                            const float* __restrict__ g2W, const float* __restrict__ g2b,
                            float* __restrict__ out) {
    __shared__ float rS[HD];
    int g = blockIdx.x;
    int j = threadIdx.x;  // 64
    int cnt = start[g + 1] - start[g];
    float inv = 1.f / fmaxf((float)cnt, 1.f);
    rS[j] = (gpart[(size_t)(4 * g + 0) * HD + j] + gpart[(size_t)(4 * g + 1) * HD + j] +
             gpart[(size_t)(4 * g + 2) * HD + j] + gpart[(size_t)(4 * g + 3) * HD + j]) * inv;
    __syncthreads();
    float a = g1b[j];
    #pragma unroll
    for (int k = 0; k < HD; ++k) a = fmaf(rS[k], g1W[k * HD + j], a);
    a = fmaxf(a, 0.f);
    float o0 = a * g2W[j * GT + 0];
    float o1 = a * g2W[j * GT + 1];
    float o2 = a * g2W[j * GT + 2];
    float o3 = a * g2W[j * GT + 3];
    #pragma unroll
    for (int off = 1; off < 64; off <<= 1) {
        o0 += __shfl_xor(o0, off, 64);
        o1 += __shfl_xor(o1, off, 64);
        o2 += __shfl_xor(o2, off, 64);
        o3 += __shfl_xor(o3, off, 64);
    }
    if (j == 0) {
        out[g * GT + 0] = o0 + g2b[0];
        out[g * GT + 1] = o1 + g2b[1];
        out[g * GT + 2] = o2 + g2b[2];
        out[g * GT + 3] = o3 + g2b[3];
    }
}

// ---------------- launch ----------------

extern "C" void kernel_launch(void* const* d_in, const int* in_sizes, int n_in,
                              void* d_out, int out_size, void* d_ws, size_t ws_size,
                              hipStream_t stream) {
    const float* x    = (const float*)d_in[0];
    const int*   ei   = (const int*)d_in[1];   // [2,E] flat: row=ei[0:E], col=ei[E:2E]
    const int*   batch= (const int*)d_in[2];
    const float* encW = (const float*)d_in[3];
    const float* encb = (const float*)d_in[4];
    const float* convW= (const float*)d_in[5]; // [L,64,64]
    const float* convb= (const float*)d_in[6]; // [L,64]
    const float* nodeW= (const float*)d_in[7];
    const float* nodeb= (const float*)d_in[8];
    const float* g1W  = (const float*)d_in[9];
    const float* g1b  = (const float*)d_in[10];
    const float* g2W  = (const float*)d_in[11];
    const float* g2b  = (const float*)d_in[12];
    float* out = (float*)d_out;

    const int N = N_NODES, E = N_EDGES;

    char* ws = (char*)d_ws;
    size_t off = 0;
    auto alloc = [&](size_t bytes) -> void* {
        void* p = ws + off;
        off += (bytes + 255) & ~(size_t)255;
        return p;
    };
    // zeroed region first (one small memset): cnt only
    int*   cnt    = (int*)alloc((size_t)N * 4);
    size_t zbytes = off;
    // rest (all fully written before read)
    int*   rank   = (int*)alloc((size_t)E * 4);
    int*   offs   = (int*)alloc((size_t)N * 4);
    int*   cnt16  = (int*)alloc((size_t)N * 4);
    float* dis    = (float*)alloc((size_t)N * 4);
    int*   bsums  = (int*)alloc(256 * 4);
    int*   start  = (int*)alloc((size_t)(N_GRAPHS + 1) * 4);
    float* gpart  = (float*)alloc((size_t)N_GRAPHS * 4 * HD * 4);
    int*   srcs   = (int*)alloc((size_t)RECS_CAP * 4);
    float* h      = (float*)alloc((size_t)(N + 1) * HD * 4);  // +1 pad row
    float* h2     = (float*)alloc((size_t)(N + 1) * HD * 4);

    hipMemsetAsync(d_ws, 0, zbytes, stream);

    const int B = 256;
    // CSR build (padded to 16, atomic-free fill via rank)
    count_edges<<<(E + B - 1) / B, B, 0, stream>>>(ei + E, cnt, rank, E);
    compute_dis<<<(N + B - 1) / B, B, 0, stream>>>(cnt, dis, cnt16, N);
    int nb1 = (N + 1023) / 1024;
    scan1<<<nb1, 256, 0, stream>>>(cnt16, offs, bsums, N);
    scan2<<<1, 256, 0, stream>>>(bsums, nb1);
    scan3<<<(N + B - 1) / B, B, 0, stream>>>(offs, bsums, N);
    fill_kernel<<<(E + B - 1) / B, B, 0, stream>>>(ei, ei + E, rank, offs, srcs, E);
    pad_fill<<<(N + B - 1) / B, B, 0, stream>>>(cnt, cnt16, offs, srcs, N);
    zero_pad_row<<<1, 256, 0, stream>>>(h, h2);
    graph_bounds<<<(N + B - 1) / B, B, 0, stream>>>(batch, start, N);

    // encoder (writes scaled features H~)
    encoder_kernel<<<(N + 15) / 16, 256, 0, stream>>>(x, encW, encb, dis, h, N);

    // GCN layers (fused aggregate + transform on scaled features), ping-pong
    float* hin = h;
    float* hot = h2;
    for (int i = 0; i < NLAYERS; ++i) {
        layer_kernel<<<N / 16, 256, 0, stream>>>(hin, offs, cnt16, (const int4*)srcs, dis,
                                                 convW + (size_t)i * HD * HD,
                                                 convb + (size_t)i * HD, hot,
                                                 (i < NLAYERS - 1) ? 1 : 0);
        float* t = hin; hin = hot; hot = t;
    }

    // heads (hin holds plain h after the last layer)
    node_head<<<(N + 31) / 32, 256, 0, stream>>>(hin, nodeW, nodeb, out, N);
    pool_kernel<<<N_GRAPHS * 4, 256, 0, stream>>>(hin, start, gpart);
    global_head<<<N_GRAPHS, 64, 0, stream>>>(gpart, start, g1W, g1b, g2W, g2b, out + (size_t)N * NT);
}

// Round 8
// 414.109 us; speedup vs baseline: 1.1742x; 1.0801x over previous
//
#include <hip/hip_runtime.h>
#include <hip/hip_fp16.h>

#define N_NODES 100000
#define N_EDGES 1250000
#define N_GRAPHS 64
#define F_INN 29
#define HD 64
#define NT 6
#define GT 4
#define NLAYERS 4
#define RECS_CAP 3000000  // >= E + 15*N worst-case padded size

#define RL(x, l) __int_as_float(__builtin_amdgcn_readlane(__float_as_int(x), l))

// ---------------- CSR construction ----------------

// count incoming edges per node AND record each edge's rank within its dest
__global__ void count_edges(const int* __restrict__ col, int* __restrict__ cnt,
                            int* __restrict__ rank, int E) {
    int e = blockIdx.x * blockDim.x + threadIdx.x;
    if (e < E) rank[e] = atomicAdd(&cnt[col[e]], 1);
}

// dis = (deg+self)^-1/2 ; cnt16 = degree padded to multiple of 16
__global__ void compute_dis(const int* __restrict__ cnt, float* __restrict__ dis,
                            int* __restrict__ cnt16, int n) {
    int i = blockIdx.x * blockDim.x + threadIdx.x;
    if (i < n) {
        int c = cnt[i];
        dis[i] = rsqrtf((float)(c + 1));
        cnt16[i] = (c + 15) & ~15;
    }
}

// exclusive scan, 3-kernel hierarchy. scan1: 1024 elems/block (4/thread, block=256)
__global__ void scan1(const int* __restrict__ in, int* __restrict__ out,
                      int* __restrict__ bsums, int n) {
    __shared__ int wsum[4];
    int tid = threadIdx.x;
    int base = blockIdx.x * 1024 + tid * 4;
    int v0 = (base + 0 < n) ? in[base + 0] : 0;
    int v1 = (base + 1 < n) ? in[base + 1] : 0;
    int v2 = (base + 2 < n) ? in[base + 2] : 0;
    int v3 = (base + 3 < n) ? in[base + 3] : 0;
    int tsum = v0 + v1 + v2 + v3;
    int incl = tsum;
    int lane = tid & 63;
    #pragma unroll
    for (int off = 1; off < 64; off <<= 1) {
        int t = __shfl_up(incl, (unsigned)off, 64);
        if (lane >= off) incl += t;
    }
    if (lane == 63) wsum[tid >> 6] = incl;
    __syncthreads();
    int woff = 0;
    for (int w = 0; w < (tid >> 6); ++w) woff += wsum[w];
    int run = woff + incl - tsum;  // exclusive prefix of this thread's first elem
    if (base + 0 < n) out[base + 0] = run; run += v0;
    if (base + 1 < n) out[base + 1] = run; run += v1;
    if (base + 2 < n) out[base + 2] = run; run += v2;
    if (base + 3 < n) out[base + 3] = run;
    if (tid == 255) bsums[blockIdx.x] = woff + incl;  // block total
}

__global__ void scan2(int* __restrict__ bsums, int nb) {
    __shared__ int s[256];
    int tid = threadIdx.x;
    int v = (tid < nb) ? bsums[tid] : 0;
    s[tid] = v;
    __syncthreads();
    #pragma unroll
    for (int off = 1; off < 256; off <<= 1) {
        int t = (tid >= off) ? s[tid - off] : 0;
        __syncthreads();
        s[tid] += t;
        __syncthreads();
    }
    if (tid < nb) bsums[tid] = s[tid] - v;  // exclusive, in place
}

__global__ void scan3(int* __restrict__ out, const int* __restrict__ bsums, int n) {
    int i = blockIdx.x * blockDim.x + threadIdx.x;
    if (i < n) out[i] += bsums[i >> 10];
}

// srcs[pos] = src node of each edge, grouped by dest (atomic-free via rank)
__global__ void fill_kernel(const int* __restrict__ row, const int* __restrict__ col,
                            const int* __restrict__ rank, const int* __restrict__ offs,
                            int* __restrict__ srcs, int E) {
    int e = blockIdx.x * blockDim.x + threadIdx.x;
    if (e >= E) return;
    srcs[offs[col[e]] + rank[e]] = row[e];
}

// pad slots (cnt..cnt16) point at the reserved zero row N_NODES
__global__ void pad_fill(const int* __restrict__ cnt, const int* __restrict__ cnt16,
                         const int* __restrict__ offs, int* __restrict__ srcs, int n) {
    int i = blockIdx.x * blockDim.x + threadIdx.x;
    if (i >= n) return;
    int base = offs[i];
    int e0 = base + cnt[i];
    int e1 = base + cnt16[i];
    for (int p = e0; p < e1; ++p) srcs[p] = N_NODES;
}

// zero the reserved pad row of both fp16 feature buffers
__global__ void zero_pad_row(__half* __restrict__ h1, __half* __restrict__ h2) {
    int t = threadIdx.x;
    if (t < HD) h1[(size_t)N_NODES * HD + t] = __float2half_rn(0.f);
    else if (t < 2 * HD) h2[(size_t)N_NODES * HD + (t - HD)] = __float2half_rn(0.f);
}

// graph boundary offsets from sorted batch; start has G+1 entries
__global__ void graph_bounds(const int* __restrict__ batch, int* __restrict__ start, int n) {
    int i = blockIdx.x * blockDim.x + threadIdx.x;
    if (i >= n) return;
    int b = batch[i];
    if (i == 0) {
        for (int g = 0; g <= b; ++g) start[g] = 0;
    } else {
        int pb = batch[i - 1];
        if (pb != b) for (int g = pb + 1; g <= b; ++g) start[g] = i;
    }
    if (i == n - 1) {
        for (int g = b + 1; g <= N_GRAPHS; ++g) start[g] = n;
    }
}

// ---------------- dense layers ----------------

// ht = fp16( dis * relu(x @ encW + encb) )   (scaled features H~)
__global__ void encoder_kernel(const float* __restrict__ x, const float* __restrict__ W,
                               const float* __restrict__ b, const float* __restrict__ dis,
                               __half* __restrict__ ht, int n) {
    __shared__ float Ws[F_INN * HD];
    __shared__ float bs[HD];
    __shared__ float xs[16 * F_INN];
    int tid = threadIdx.x;
    for (int i = tid; i < F_INN * HD; i += 256) Ws[i] = W[i];
    if (tid < HD) bs[tid] = b[tid];
    int n0 = blockIdx.x * 16;
    for (int i = tid; i < 16 * F_INN; i += 256) {
        int nn = n0 + i / F_INN;
        xs[i] = (nn < n) ? x[(size_t)nn * F_INN + (i % F_INN)] : 0.f;
    }
    __syncthreads();
    #pragma unroll
    for (int it = 0; it < 4; ++it) {
        int l = it * 4 + (tid >> 6);
        int j = tid & 63;
        int nn = n0 + l;
        if (nn < n) {
            float a = bs[j];
            #pragma unroll
            for (int k = 0; k < F_INN; ++k) a = fmaf(xs[l * F_INN + k], Ws[k * HD + j], a);
            ht[(size_t)nn * HD + j] = __float2half_rn(dis[nn] * fmaxf(a, 0.f));
        }
    }
}

__device__ __forceinline__ float4 cvtrow(uint2 u) {
    float2 a = __half22float2(*reinterpret_cast<const __half2*>(&u.x));
    float2 b = __half22float2(*reinterpret_cast<const __half2*>(&u.y));
    return make_float4(a.x, a.y, b.x, b.y);
}

#define ROW16(src) (*reinterpret_cast<const uint2*>(&ht[(size_t)(src) * HD + f]))
#define ACC4(acc, r0, r1, r2, r3) { \
    float4 t0 = cvtrow(r0), t1 = cvtrow(r1), t2 = cvtrow(r2), t3 = cvtrow(r3); \
    acc.x += (t0.x + t1.x) + (t2.x + t3.x); \
    acc.y += (t0.y + t1.y) + (t2.y + t3.y); \
    acc.z += (t0.z + t1.z) + (t2.z + t3.z); \
    acc.w += (t0.w + t1.w) + (t2.w + t3.w); }

// Fused GCN layer on fp16 scaled features: agg = sum_src H~[src] + H~[node].
// Wave owns 4 nodes, interleaved gathers (16 half-rows of 128B in flight).
// Matvec joint over 4 nodes via LDS Ws + v_readlane broadcast.
// MODE 0: hout16 = fp16(dn * relu(dn*(agg@W)+b))        (intermediate layer)
// MODE 1: h32 = relu(dn*(agg@W)+b); pred = h32@nodeW+nodeb  (final layer)
template <int MODE>
__global__ void layer_kernel(const __half* __restrict__ ht,
                             const int* __restrict__ offs, const int* __restrict__ cnt16,
                             const int4* __restrict__ srcs4,
                             const float* __restrict__ dis,
                             const float* __restrict__ W, const float* __restrict__ b,
                             __half* __restrict__ hout16, float* __restrict__ h32,
                             const float* __restrict__ nodeW, const float* __restrict__ nodeb,
                             float* __restrict__ pred) {
    __shared__ float Ws[HD * HD];
    __shared__ float bs[HD];
    int tid = threadIdx.x;
    for (int i = tid; i < HD * HD; i += 256) Ws[i] = W[i];
    if (tid < HD) bs[tid] = b[tid];
    __syncthreads();
    int wave = tid >> 6;
    int lane = tid & 63;
    int j = lane;
    float bb = bs[j];
    float wn0, wn1, wn2, wn3, wn4, wn5, bn;
    if (MODE == 1) {
        wn0 = nodeW[j * NT + 0]; wn1 = nodeW[j * NT + 1]; wn2 = nodeW[j * NT + 2];
        wn3 = nodeW[j * NT + 3]; wn4 = nodeW[j * NT + 4]; wn5 = nodeW[j * NT + 5];
        bn = (lane < NT) ? nodeb[lane] : 0.f;
    }
    int q = lane >> 4;        // edge subgroup 0..3
    int f = (lane & 15) * 4;  // feature offset (in half elements)
    int node0 = blockIdx.x * 16 + wave * 4;  // grid*16 == N exactly
    int nA = node0, nB = node0 + 1, nC = node0 + 2, nD = node0 + 3;
    int pA = offs[nA], eA = pA + cnt16[nA];
    int pB = offs[nB], eB = pB + cnt16[nB];
    int pC = offs[nC], eC = pC + cnt16[nC];
    int pD = offs[nD], eD = pD + cnt16[nD];
    float4 accA = {0.f, 0.f, 0.f, 0.f}, accB = accA, accC = accA, accD = accA;

    while ((pA < eA) | (pB < eB) | (pC < eC) | (pD < eD)) {
        bool cA = pA < eA, cB = pB < eB, cC = pC < eC, cD = pD < eD;
        int4 sA, sB, sC, sD;
        if (cA) sA = srcs4[(pA >> 2) + q];
        if (cB) sB = srcs4[(pB >> 2) + q];
        if (cC) sC = srcs4[(pC >> 2) + q];
        if (cD) sD = srcs4[(pD >> 2) + q];
        uint2 rA0, rA1, rA2, rA3, rB0, rB1, rB2, rB3;
        uint2 rC0, rC1, rC2, rC3, rD0, rD1, rD2, rD3;
        if (cA) { rA0 = ROW16(sA.x); rA1 = ROW16(sA.y); rA2 = ROW16(sA.z); rA3 = ROW16(sA.w); }
        if (cB) { rB0 = ROW16(sB.x); rB1 = ROW16(sB.y); rB2 = ROW16(sB.z); rB3 = ROW16(sB.w); }
        if (cC) { rC0 = ROW16(sC.x); rC1 = ROW16(sC.y); rC2 = ROW16(sC.z); rC3 = ROW16(sC.w); }
        if (cD) { rD0 = ROW16(sD.x); rD1 = ROW16(sD.y); rD2 = ROW16(sD.z); rD3 = ROW16(sD.w); }
        if (cA) { ACC4(accA, rA0, rA1, rA2, rA3); pA += 16; }
        if (cB) { ACC4(accB, rB0, rB1, rB2, rB3); pB += 16; }
        if (cC) { ACC4(accC, rC0, rC1, rC2, rC3); pC += 16; }
        if (cD) { ACC4(accD, rD0, rD1, rD2, rD3); pD += 16; }
    }
    // butterfly over quarters (bits 4,5): all lanes get the full row sums
    #pragma unroll
    for (int off = 16; off < 64; off <<= 1) {
        accA.x += __shfl_xor(accA.x, off, 64);
        accA.y += __shfl_xor(accA.y, off, 64);
        accA.z += __shfl_xor(accA.z, off, 64);
        accA.w += __shfl_xor(accA.w, off, 64);
        accB.x += __shfl_xor(accB.x, off, 64);
        accB.y += __shfl_xor(accB.y, off, 64);
        accB.z += __shfl_xor(accB.z, off, 64);
        accB.w += __shfl_xor(accB.w, off, 64);
        accC.x += __shfl_xor(accC.x, off, 64);
        accC.y += __shfl_xor(accC.y, off, 64);
        accC.z += __shfl_xor(accC.z, off, 64);
        accC.w += __shfl_xor(accC.w, off, 64);
        accD.x += __shfl_xor(accD.x, off, 64);
        accD.y += __shfl_xor(accD.y, off, 64);
        accD.z += __shfl_xor(accD.z, off, 64);
        accD.w += __shfl_xor(accD.w, off, 64);
    }
    // self terms
    {
        float4 hA = cvtrow(ROW16(nA)), hB = cvtrow(ROW16(nB));
        float4 hC = cvtrow(ROW16(nC)), hD = cvtrow(ROW16(nD));
        accA.x += hA.x; accA.y += hA.y; accA.z += hA.z; accA.w += hA.w;
        accB.x += hB.x; accB.y += hB.y; accB.z += hB.z; accB.w += hB.w;
        accC.x += hC.x; accC.y += hC.y; accC.z += hC.z; accC.w += hC.w;
        accD.x += hD.x; accD.y += hD.y; accD.z += hD.z; accD.w += hD.w;
    }
    float dnA = dis[nA], dnB = dis[nB], dnC = dis[nC], dnD = dis[nD];
    // joint matvec: out_j = sum_k agg[k] * W[k][j]; agg[4kk+c] lives in lane kk comp c
    float aA0 = 0.f, aA1 = 0.f, aB0 = 0.f, aB1 = 0.f;
    float aC0 = 0.f, aC1 = 0.f, aD0 = 0.f, aD1 = 0.f;
    #pragma unroll
    for (int kk = 0; kk < 16; ++kk) {
        const float w0 = Ws[(4 * kk + 0) * HD + j];
        const float w1 = Ws[(4 * kk + 1) * HD + j];
        const float w2 = Ws[(4 * kk + 2) * HD + j];
        const float w3 = Ws[(4 * kk + 3) * HD + j];
        aA0 = fmaf(RL(accA.x, kk), w0, aA0);
        aA1 = fmaf(RL(accA.y, kk), w1, aA1);
        aA0 = fmaf(RL(accA.z, kk), w2, aA0);
        aA1 = fmaf(RL(accA.w, kk), w3, aA1);
        aB0 = fmaf(RL(accB.x, kk), w0, aB0);
        aB1 = fmaf(RL(accB.y, kk), w1, aB1);
        aB0 = fmaf(RL(accB.z, kk), w2, aB0);
        aB1 = fmaf(RL(accB.w, kk), w3, aB1);
        aC0 = fmaf(RL(accC.x, kk), w0, aC0);
        aC1 = fmaf(RL(accC.y, kk), w1, aC1);
        aC0 = fmaf(RL(accC.z, kk), w2, aC0);
        aC1 = fmaf(RL(accC.w, kk), w3, aC1);
        aD0 = fmaf(RL(accD.x, kk), w0, aD0);
        aD1 = fmaf(RL(accD.y, kk), w1, aD1);
        aD0 = fmaf(RL(accD.z, kk), w2, aD0);
        aD1 = fmaf(RL(accD.w, kk), w3, aD1);
    }
    float oA = fmaxf(fmaf(dnA, aA0 + aA1, bb), 0.f);
    float oB = fmaxf(fmaf(dnB, aB0 + aB1, bb), 0.f);
    float oC = fmaxf(fmaf(dnC, aC0 + aC1, bb), 0.f);
    float oD = fmaxf(fmaf(dnD, aD0 + aD1, bb), 0.f);
    if (MODE == 0) {
        hout16[(size_t)nA * HD + j] = __float2half_rn(oA * dnA);
        hout16[(size_t)nB * HD + j] = __float2half_rn(oB * dnB);
        hout16[(size_t)nC * HD + j] = __float2half_rn(oC * dnC);
        hout16[(size_t)nD * HD + j] = __float2half_rn(oD * dnD);
    } else {
        h32[(size_t)nA * HD + j] = oA;
        h32[(size_t)nB * HD + j] = oB;
        h32[(size_t)nC * HD + j] = oC;
        h32[(size_t)nD * HD + j] = oD;
        // fused node head: pred[n][t] = sum_j o_j * nodeW[j][t] + nodeb[t]
        #pragma unroll
        for (int v = 0; v < 4; ++v) {
            float o = (v == 0) ? oA : (v == 1) ? oB : (v == 2) ? oC : oD;
            int nn = node0 + v;
            float p0 = o * wn0, p1 = o * wn1, p2 = o * wn2;
            float p3 = o * wn3, p4 = o * wn4, p5 = o * wn5;
            #pragma unroll
            for (int off = 1; off < 64; off <<= 1) {
                p0 += __shfl_xor(p0, off, 64);
                p1 += __shfl_xor(p1, off, 64);
                p2 += __shfl_xor(p2, off, 64);
                p3 += __shfl_xor(p3, off, 64);
                p4 += __shfl_xor(p4, off, 64);
                p5 += __shfl_xor(p5, off, 64);
            }
            if (lane < NT) {
                float pv = (lane == 0) ? p0 : (lane == 1) ? p1 : (lane == 2) ? p2
                         : (lane == 3) ? p3 : (lane == 4) ? p4 : p5;
                pred[(size_t)nn * NT + lane] = pv + bn;
            }
        }
    }
}

// atomic-free pooling: 4 blocks per graph, each sums a contiguous quarter-range
__global__ void pool_kernel(const float* __restrict__ h, const int* __restrict__ start,
                            float* __restrict__ gpart) {
    __shared__ float red[4][HD];
    int g = blockIdx.x >> 2, q = blockIdx.x & 3;
    int s0 = start[g], e0 = start[g + 1];
    int len = e0 - s0;
    int qs = s0 + (len * q) / 4;
    int qe = s0 + (len * (q + 1)) / 4;
    int wave = threadIdx.x >> 6, lane = threadIdx.x & 63;
    float acc = 0.f;
    for (int r = qs + wave; r < qe; r += 4) acc += h[(size_t)r * HD + lane];
    red[wave][lane] = acc;
    __syncthreads();
    if (wave == 0)
        gpart[(size_t)blockIdx.x * HD + lane] =
            red[0][lane] + red[1][lane] + red[2][lane] + red[3][lane];
}

// gemb = sum(gpart quarters)/count; out = relu(gemb@g1W+g1b)@g2W + g2b
__global__ void global_head(const float* __restrict__ gpart, const int* __restrict__ start,
                            const float* __restrict__ g1W, const float* __restrict__ g1b,
                            const float* __restrict__ g2W, const float* __restrict__ g2b,
                            float* __restrict__ out) {
    __shared__ float rS[HD];
    int g = blockIdx.x;
    int j = threadIdx.x;  // 64
    int cnt = start[g + 1] - start[g];
    float inv = 1.f / fmaxf((float)cnt, 1.f);
    rS[j] = (gpart[(size_t)(4 * g + 0) * HD + j] + gpart[(size_t)(4 * g + 1) * HD + j] +
             gpart[(size_t)(4 * g + 2) * HD + j] + gpart[(size_t)(4 * g + 3) * HD + j]) * inv;
    __syncthreads();
    float a = g1b[j];
    #pragma unroll
    for (int k = 0; k < HD; ++k) a = fmaf(rS[k], g1W[k * HD + j], a);
    a = fmaxf(a, 0.f);
    float o0 = a * g2W[j * GT + 0];
    float o1 = a * g2W[j * GT + 1];
    float o2 = a * g2W[j * GT + 2];
    float o3 = a * g2W[j * GT + 3];
    #pragma unroll
    for (int off = 1; off < 64; off <<= 1) {
        o0 += __shfl_xor(o0, off, 64);
        o1 += __shfl_xor(o1, off, 64);
        o2 += __shfl_xor(o2, off, 64);
        o3 += __shfl_xor(o3, off, 64);
    }
    if (j == 0) {
        out[g * GT + 0] = o0 + g2b[0];
        out[g * GT + 1] = o1 + g2b[1];
        out[g * GT + 2] = o2 + g2b[2];
        out[g * GT + 3] = o3 + g2b[3];
    }
}

// ---------------- launch ----------------

extern "C" void kernel_launch(void* const* d_in, const int* in_sizes, int n_in,
                              void* d_out, int out_size, void* d_ws, size_t ws_size,
                              hipStream_t stream) {
    const float* x    = (const float*)d_in[0];
    const int*   ei   = (const int*)d_in[1];   // [2,E] flat: row=ei[0:E], col=ei[E:2E]
    const int*   batch= (const int*)d_in[2];
    const float* encW = (const float*)d_in[3];
    const float* encb = (const float*)d_in[4];
    const float* convW= (const float*)d_in[5]; // [L,64,64]
    const float* convb= (const float*)d_in[6]; // [L,64]
    const float* nodeW= (const float*)d_in[7];
    const float* nodeb= (const float*)d_in[8];
    const float* g1W  = (const float*)d_in[9];
    const float* g1b  = (const float*)d_in[10];
    const float* g2W  = (const float*)d_in[11];
    const float* g2b  = (const float*)d_in[12];
    float* out = (float*)d_out;

    const int N = N_NODES, E = N_EDGES;

    char* ws = (char*)d_ws;
    size_t off = 0;
    auto alloc = [&](size_t bytes) -> void* {
        void* p = ws + off;
        off += (bytes + 255) & ~(size_t)255;
        return p;
    };
    // zeroed region first (one small memset): cnt only
    int*   cnt    = (int*)alloc((size_t)N * 4);
    size_t zbytes = off;
    // rest (all fully written before read)
    int*   rank   = (int*)alloc((size_t)E * 4);
    int*   offs   = (int*)alloc((size_t)N * 4);
    int*   cnt16  = (int*)alloc((size_t)N * 4);
    float* dis    = (float*)alloc((size_t)N * 4);
    int*   bsums  = (int*)alloc(256 * 4);
    int*   start  = (int*)alloc((size_t)(N_GRAPHS + 1) * 4);
    float* gpart  = (float*)alloc((size_t)N_GRAPHS * 4 * HD * 4);
    int*   srcs   = (int*)alloc((size_t)RECS_CAP * 4);
    __half* ht1   = (__half*)alloc((size_t)(N + 1) * HD * 2);  // +1 pad row
    __half* ht2   = (__half*)alloc((size_t)(N + 1) * HD * 2);
    float* h32    = (float*)alloc((size_t)N * HD * 4);

    hipMemsetAsync(d_ws, 0, zbytes, stream);

    const int B = 256;
    // CSR build (padded to 16, atomic-free fill via rank)
    count_edges<<<(E + B - 1) / B, B, 0, stream>>>(ei + E, cnt, rank, E);
    compute_dis<<<(N + B - 1) / B, B, 0, stream>>>(cnt, dis, cnt16, N);
    int nb1 = (N + 1023) / 1024;
    scan1<<<nb1, 256, 0, stream>>>(cnt16, offs, bsums, N);
    scan2<<<1, 256, 0, stream>>>(bsums, nb1);
    scan3<<<(N + B - 1) / B, B, 0, stream>>>(offs, bsums, N);
    fill_kernel<<<(E + B - 1) / B, B, 0, stream>>>(ei, ei + E, rank, offs, srcs, E);
    pad_fill<<<(N + B - 1) / B, B, 0, stream>>>(cnt, cnt16, offs, srcs, N);
    zero_pad_row<<<1, 256, 0, stream>>>(ht1, ht2);
    graph_bounds<<<(N + B - 1) / B, B, 0, stream>>>(batch, start, N);

    // encoder (writes fp16 scaled features H~)
    encoder_kernel<<<(N + 15) / 16, 256, 0, stream>>>(x, encW, encb, dis, ht1, N);

    // GCN layers 0..2 (fp16 -> fp16), layer 3 (fp16 -> fp32 h + fused node head)
    __half* hin = ht1;
    __half* hot = ht2;
    for (int i = 0; i < NLAYERS - 1; ++i) {
        layer_kernel<0><<<N / 16, 256, 0, stream>>>(hin, offs, cnt16, (const int4*)srcs, dis,
                                                    convW + (size_t)i * HD * HD,
                                                    convb + (size_t)i * HD,
                                                    hot, nullptr, nullptr, nullptr, nullptr);
        __half* t = hin; hin = hot; hot = t;
    }
    layer_kernel<1><<<N / 16, 256, 0, stream>>>(hin, offs, cnt16, (const int4*)srcs, dis,
                                                convW + (size_t)(NLAYERS - 1) * HD * HD,
                                                convb + (size_t)(NLAYERS - 1) * HD,
                                                nullptr, h32, nodeW, nodeb, out);

    // heads
    pool_kernel<<<N_GRAPHS * 4, 256, 0, stream>>>(h32, start, gpart);
    global_head<<<N_GRAPHS, 64, 0, stream>>>(gpart, start, g1W, g1b, g2W, g2b, out + (size_t)N * NT);
}

// Round 9
// 319.834 us; speedup vs baseline: 1.5203x; 1.2948x over previous
//
#include <hip/hip_runtime.h>
#include <hip/hip_fp16.h>

#define N_NODES 100000
#define N_EDGES 1250000
#define N_GRAPHS 64
#define F_INN 29
#define HD 64
#define NT 6
#define GT 4
#define NLAYERS 4
#define RECS_CAP 3000000  // >= E + 15*N worst-case padded size

typedef __attribute__((ext_vector_type(8))) _Float16 f16x8;
typedef __attribute__((ext_vector_type(4))) float f32x4;

// ---------------- CSR construction ----------------

__global__ void count_edges(const int* __restrict__ col, int* __restrict__ cnt,
                            int* __restrict__ rank, int E) {
    int e = blockIdx.x * blockDim.x + threadIdx.x;
    if (e < E) rank[e] = atomicAdd(&cnt[col[e]], 1);
}

__global__ void compute_dis(const int* __restrict__ cnt, float* __restrict__ dis,
                            int* __restrict__ cnt16, int n) {
    int i = blockIdx.x * blockDim.x + threadIdx.x;
    if (i < n) {
        int c = cnt[i];
        dis[i] = rsqrtf((float)(c + 1));
        cnt16[i] = (c + 15) & ~15;
    }
}

__global__ void scan1(const int* __restrict__ in, int* __restrict__ out,
                      int* __restrict__ bsums, int n) {
    __shared__ int wsum[4];
    int tid = threadIdx.x;
    int base = blockIdx.x * 1024 + tid * 4;
    int v0 = (base + 0 < n) ? in[base + 0] : 0;
    int v1 = (base + 1 < n) ? in[base + 1] : 0;
    int v2 = (base + 2 < n) ? in[base + 2] : 0;
    int v3 = (base + 3 < n) ? in[base + 3] : 0;
    int tsum = v0 + v1 + v2 + v3;
    int incl = tsum;
    int lane = tid & 63;
    #pragma unroll
    for (int off = 1; off < 64; off <<= 1) {
        int t = __shfl_up(incl, (unsigned)off, 64);
        if (lane >= off) incl += t;
    }
    if (lane == 63) wsum[tid >> 6] = incl;
    __syncthreads();
    int woff = 0;
    for (int w = 0; w < (tid >> 6); ++w) woff += wsum[w];
    int run = woff + incl - tsum;
    if (base + 0 < n) out[base + 0] = run; run += v0;
    if (base + 1 < n) out[base + 1] = run; run += v1;
    if (base + 2 < n) out[base + 2] = run; run += v2;
    if (base + 3 < n) out[base + 3] = run;
    if (tid == 255) bsums[blockIdx.x] = woff + incl;
}

__global__ void scan2(int* __restrict__ bsums, int nb) {
    __shared__ int s[256];
    int tid = threadIdx.x;
    int v = (tid < nb) ? bsums[tid] : 0;
    s[tid] = v;
    __syncthreads();
    #pragma unroll
    for (int off = 1; off < 256; off <<= 1) {
        int t = (tid >= off) ? s[tid - off] : 0;
        __syncthreads();
        s[tid] += t;
        __syncthreads();
    }
    if (tid < nb) bsums[tid] = s[tid] - v;
}

__global__ void scan3(int* __restrict__ out, const int* __restrict__ bsums, int n) {
    int i = blockIdx.x * blockDim.x + threadIdx.x;
    if (i < n) out[i] += bsums[i >> 10];
}

__global__ void fill_kernel(const int* __restrict__ row, const int* __restrict__ col,
                            const int* __restrict__ rank, const int* __restrict__ offs,
                            int* __restrict__ srcs, int E) {
    int e = blockIdx.x * blockDim.x + threadIdx.x;
    if (e >= E) return;
    srcs[offs[col[e]] + rank[e]] = row[e];
}

__global__ void pad_fill(const int* __restrict__ cnt, const int* __restrict__ cnt16,
                         const int* __restrict__ offs, int* __restrict__ srcs, int n) {
    int i = blockIdx.x * blockDim.x + threadIdx.x;
    if (i >= n) return;
    int base = offs[i];
    int e0 = base + cnt[i];
    int e1 = base + cnt16[i];
    for (int p = e0; p < e1; ++p) srcs[p] = N_NODES;
}

__global__ void zero_pad_row(__half* __restrict__ h1, __half* __restrict__ h2) {
    int t = threadIdx.x;
    if (t < HD) h1[(size_t)N_NODES * HD + t] = __float2half_rn(0.f);
    else if (t < 2 * HD) h2[(size_t)N_NODES * HD + (t - HD)] = __float2half_rn(0.f);
}

__global__ void graph_bounds(const int* __restrict__ batch, int* __restrict__ start, int n) {
    int i = blockIdx.x * blockDim.x + threadIdx.x;
    if (i >= n) return;
    int b = batch[i];
    if (i == 0) {
        for (int g = 0; g <= b; ++g) start[g] = 0;
    } else {
        int pb = batch[i - 1];
        if (pb != b) for (int g = pb + 1; g <= b; ++g) start[g] = i;
    }
    if (i == n - 1) {
        for (int g = b + 1; g <= N_GRAPHS; ++g) start[g] = n;
    }
}

// Pre-pack conv weights into MFMA B-fragment order (fp16), 512 x 16B slots/layer.
// slot s: jt=s>>7, ks=(s>>6)&1, l=s&63 -> halfs i=0..7 = W[ks*32+(l>>4)*8+i][jt*16+(l&15)]
__global__ void prepack_W(const float* __restrict__ convW, uint4* __restrict__ wfrag) {
    int layer = blockIdx.x;
    const float* W = convW + (size_t)layer * HD * HD;
    uint4* out = wfrag + (size_t)layer * 512;
    for (int s = threadIdx.x; s < 512; s += 256) {
        int jt = s >> 7, ks = (s >> 6) & 1, l = s & 63;
        int j = jt * 16 + (l & 15);
        int k0 = ks * 32 + (l >> 4) * 8;
        __align__(16) __half hh[8];
        #pragma unroll
        for (int i = 0; i < 8; ++i) hh[i] = __float2half_rn(W[(size_t)(k0 + i) * HD + j]);
        out[s] = *reinterpret_cast<const uint4*>(hh);
    }
}

// ---------------- dense layers ----------------

// ht = fp16( dis * relu(x @ encW + encb) )
__global__ void encoder_kernel(const float* __restrict__ x, const float* __restrict__ W,
                               const float* __restrict__ b, const float* __restrict__ dis,
                               __half* __restrict__ ht, int n) {
    __shared__ float Ws[F_INN * HD];
    __shared__ float bs[HD];
    __shared__ float xs[16 * F_INN];
    int tid = threadIdx.x;
    for (int i = tid; i < F_INN * HD; i += 256) Ws[i] = W[i];
    if (tid < HD) bs[tid] = b[tid];
    int n0 = blockIdx.x * 16;
    for (int i = tid; i < 16 * F_INN; i += 256) {
        int nn = n0 + i / F_INN;
        xs[i] = (nn < n) ? x[(size_t)nn * F_INN + (i % F_INN)] : 0.f;
    }
    __syncthreads();
    #pragma unroll
    for (int it = 0; it < 4; ++it) {
        int l = it * 4 + (tid >> 6);
        int j = tid & 63;
        int nn = n0 + l;
        if (nn < n) {
            float a = bs[j];
            #pragma unroll
            for (int k = 0; k < F_INN; ++k) a = fmaf(xs[l * F_INN + k], Ws[k * HD + j], a);
            ht[(size_t)nn * HD + j] = __float2half_rn(dis[nn] * fmaxf(a, 0.f));
        }
    }
}

__device__ __forceinline__ float4 cvtrow(uint2 u) {
    float2 a = __half22float2(*reinterpret_cast<const __half2*>(&u.x));
    float2 b = __half22float2(*reinterpret_cast<const __half2*>(&u.y));
    return make_float4(a.x, a.y, b.x, b.y);
}

#define ROW16(src) (*reinterpret_cast<const uint2*>(&ht[(size_t)(src) * HD + fh]))
// packed fp16 partial sum of 4 rows, then fp32 accumulate
#define ACCP(acc, r0, r1, r2, r3) { \
    __half2 a0 = *(__half2*)&r0.x, a1 = *(__half2*)&r1.x; \
    __half2 a2 = *(__half2*)&r2.x, a3 = *(__half2*)&r3.x; \
    __half2 b0 = *(__half2*)&r0.y, b1 = *(__half2*)&r1.y; \
    __half2 b2 = *(__half2*)&r2.y, b3 = *(__half2*)&r3.y; \
    __half2 s0 = __hadd2(__hadd2(a0, a1), __hadd2(a2, a3)); \
    __half2 s1 = __hadd2(__hadd2(b0, b1), __hadd2(b2, b3)); \
    float2 f0 = __half22float2(s0), f1 = __half22float2(s1); \
    acc.x += f0.x; acc.y += f0.y; acc.z += f1.x; acc.w += f1.y; }

// Fused GCN layer: per-wave gather of 4 nodes (fp16 rows, packed partial sums),
// butterfly reduce, agg rows -> LDS (fp16), then block-cooperative MFMA matvec
// (16 nodes x 64 @ 64x64 = 8x mfma_f32_16x16x32_f16, one j-tile per wave).
// out = relu(dn*(agg@W)+b), optionally *dn (scaled features for next layer).
__global__ void layer_kernel(const __half* __restrict__ ht,
                             const int* __restrict__ offs, const int* __restrict__ cnt16,
                             const int4* __restrict__ srcs4,
                             const float* __restrict__ dis,
                             const uint4* __restrict__ wfragL, const float* __restrict__ bias,
                             __half* __restrict__ hout, int scaleOut) {
    __shared__ uint4 WfS[512];          // 8KB: B-fragments
    __shared__ __half aggS[16 * 72];    // 16 agg rows, stride 72 halfs (bank-safe)
    int tid = threadIdx.x;
    WfS[tid] = wfragL[tid];
    WfS[tid + 256] = wfragL[tid + 256];
    int wave = tid >> 6;
    int lane = tid & 63;
    int q = lane >> 4;         // edge subgroup 0..3
    int fh = (lane & 15) * 4;  // feature offset in halfs
    int node0 = blockIdx.x * 16 + wave * 4;  // grid*16 == N exactly
    int nA = node0, nB = node0 + 1, nC = node0 + 2, nD = node0 + 3;
    int pA = offs[nA], eA = pA + cnt16[nA];
    int pB = offs[nB], eB = pB + cnt16[nB];
    int pC = offs[nC], eC = pC + cnt16[nC];
    int pD = offs[nD], eD = pD + cnt16[nD];
    float4 accA = {0.f, 0.f, 0.f, 0.f}, accB = accA, accC = accA, accD = accA;

    while ((pA < eA) | (pB < eB) | (pC < eC) | (pD < eD)) {
        bool cA = pA < eA, cB = pB < eB, cC = pC < eC, cD = pD < eD;
        int4 sA, sB, sC, sD;
        if (cA) sA = srcs4[(pA >> 2) + q];
        if (cB) sB = srcs4[(pB >> 2) + q];
        if (cC) sC = srcs4[(pC >> 2) + q];
        if (cD) sD = srcs4[(pD >> 2) + q];
        uint2 rA0, rA1, rA2, rA3, rB0, rB1, rB2, rB3;
        uint2 rC0, rC1, rC2, rC3, rD0, rD1, rD2, rD3;
        if (cA) { rA0 = ROW16(sA.x); rA1 = ROW16(sA.y); rA2 = ROW16(sA.z); rA3 = ROW16(sA.w); }
        if (cB) { rB0 = ROW16(sB.x); rB1 = ROW16(sB.y); rB2 = ROW16(sB.z); rB3 = ROW16(sB.w); }
        if (cC) { rC0 = ROW16(sC.x); rC1 = ROW16(sC.y); rC2 = ROW16(sC.z); rC3 = ROW16(sC.w); }
        if (cD) { rD0 = ROW16(sD.x); rD1 = ROW16(sD.y); rD2 = ROW16(sD.z); rD3 = ROW16(sD.w); }
        if (cA) { ACCP(accA, rA0, rA1, rA2, rA3); pA += 16; }
        if (cB) { ACCP(accB, rB0, rB1, rB2, rB3); pB += 16; }
        if (cC) { ACCP(accC, rC0, rC1, rC2, rC3); pC += 16; }
        if (cD) { ACCP(accD, rD0, rD1, rD2, rD3); pD += 16; }
    }
    // butterfly over quarters (bits 4,5): all lanes get the full row sums
    #pragma unroll
    for (int off = 16; off < 64; off <<= 1) {
        accA.x += __shfl_xor(accA.x, off, 64);
        accA.y += __shfl_xor(accA.y, off, 64);
        accA.z += __shfl_xor(accA.z, off, 64);
        accA.w += __shfl_xor(accA.w, off, 64);
        accB.x += __shfl_xor(accB.x, off, 64);
        accB.y += __shfl_xor(accB.y, off, 64);
        accB.z += __shfl_xor(accB.z, off, 64);
        accB.w += __shfl_xor(accB.w, off, 64);
        accC.x += __shfl_xor(accC.x, off, 64);
        accC.y += __shfl_xor(accC.y, off, 64);
        accC.z += __shfl_xor(accC.z, off, 64);
        accC.w += __shfl_xor(accC.w, off, 64);
        accD.x += __shfl_xor(accD.x, off, 64);
        accD.y += __shfl_xor(accD.y, off, 64);
        accD.z += __shfl_xor(accD.z, off, 64);
        accD.w += __shfl_xor(accD.w, off, 64);
    }
    // self terms (fp32 path)
    {
        float4 hA = cvtrow(ROW16(nA)), hB = cvtrow(ROW16(nB));
        float4 hC = cvtrow(ROW16(nC)), hD = cvtrow(ROW16(nD));
        accA.x += hA.x; accA.y += hA.y; accA.z += hA.z; accA.w += hA.w;
        accB.x += hB.x; accB.y += hB.y; accB.z += hB.z; accB.w += hB.w;
        accC.x += hC.x; accC.y += hC.y; accC.z += hC.z; accC.w += hC.w;
        accD.x += hD.x; accD.y += hD.y; accD.z += hD.z; accD.w += hD.w;
    }
    // stash agg rows (fp16) in LDS: q==0 lanes cover all 64 features per node
    if (q == 0) {
        __half2 p;
        uint2 w;
        p = __floats2half2_rn(accA.x, accA.y); w.x = *(unsigned*)&p;
        p = __floats2half2_rn(accA.z, accA.w); w.y = *(unsigned*)&p;
        *reinterpret_cast<uint2*>(&aggS[(wave * 4 + 0) * 72 + fh]) = w;
        p = __floats2half2_rn(accB.x, accB.y); w.x = *(unsigned*)&p;
        p = __floats2half2_rn(accB.z, accB.w); w.y = *(unsigned*)&p;
        *reinterpret_cast<uint2*>(&aggS[(wave * 4 + 1) * 72 + fh]) = w;
        p = __floats2half2_rn(accC.x, accC.y); w.x = *(unsigned*)&p;
        p = __floats2half2_rn(accC.z, accC.w); w.y = *(unsigned*)&p;
        *reinterpret_cast<uint2*>(&aggS[(wave * 4 + 2) * 72 + fh]) = w;
        p = __floats2half2_rn(accD.x, accD.y); w.x = *(unsigned*)&p;
        p = __floats2half2_rn(accD.z, accD.w); w.y = *(unsigned*)&p;
        *reinterpret_cast<uint2*>(&aggS[(wave * 4 + 3) * 72 + fh]) = w;
    }
    __syncthreads();
    // MFMA: wave owns j-tile = wave; A row = lane&15 (node), k = (lane>>4)*8+i
    f32x4 c = {0.f, 0.f, 0.f, 0.f};
    #pragma unroll
    for (int ks = 0; ks < 2; ++ks) {
        f16x8 a = *reinterpret_cast<const f16x8*>(&aggS[(lane & 15) * 72 + ks * 32 + (lane >> 4) * 8]);
        f16x8 b = *reinterpret_cast<const f16x8*>(&WfS[(wave * 2 + ks) * 64 + lane]);
        c = __builtin_amdgcn_mfma_f32_16x16x32_f16(a, b, c, 0, 0, 0);
    }
    // epilogue: D col=lane&15, row=(lane>>4)*4+i
    int j = wave * 16 + (lane & 15);
    float bj = bias[j];
    #pragma unroll
    for (int i = 0; i < 4; ++i) {
        int n16 = (lane >> 4) * 4 + i;
        int node = blockIdx.x * 16 + n16;
        float dn = dis[node];
        float o = fmaxf(fmaf(dn, c[i], bj), 0.f);
        if (scaleOut) o *= dn;
        hout[(size_t)node * HD + j] = __float2half_rn(o);
    }
}

// pred_node = h @ nodeW + nodeb from fp16 h (streaming)
__global__ void node_head16(const __half* __restrict__ h, const float* __restrict__ W,
                            const float* __restrict__ b, float* __restrict__ out, int n) {
    __shared__ float Ws[HD * NT];
    __shared__ float bs[NT];
    __shared__ float hs[32 * 65];
    int tid = threadIdx.x;
    for (int i = tid; i < HD * NT; i += 256) Ws[i] = W[i];
    if (tid < NT) bs[tid] = b[tid];
    int n0 = blockIdx.x * 32;
    const unsigned* hrow = reinterpret_cast<const unsigned*>(&h[(size_t)n0 * HD]);
    for (int i = tid; i < 32 * HD / 2; i += 256) {
        unsigned u = hrow[i];
        float2 f = __half22float2(*reinterpret_cast<const __half2*>(&u));
        int el = i * 2;
        int row = el >> 6, colc = el & 63;
        hs[row * 65 + colc] = f.x;
        hs[row * 65 + colc + 1] = f.y;
    }
    __syncthreads();
    int l = tid >> 3, t = tid & 7;
    int nn = n0 + l;
    if (nn < n && t < NT) {
        float a = bs[t];
        #pragma unroll
        for (int k = 0; k < HD; ++k) a = fmaf(hs[l * 65 + k], Ws[k * NT + t], a);
        out[(size_t)nn * NT + t] = a;
    }
}

// atomic-free pooling from fp16 h: 4 blocks per graph
__global__ void pool16(const __half* __restrict__ h, const int* __restrict__ start,
                       float* __restrict__ gpart) {
    __shared__ float red[4][HD];
    int g = blockIdx.x >> 2, q = blockIdx.x & 3;
    int s0 = start[g], e0 = start[g + 1];
    int len = e0 - s0;
    int qs = s0 + (len * q) / 4;
    int qe = s0 + (len * (q + 1)) / 4;
    int wave = threadIdx.x >> 6, lane = threadIdx.x & 63;
    float acc = 0.f;
    for (int r = qs + wave; r < qe; r += 4) acc += __half2float(h[(size_t)r * HD + lane]);
    red[wave][lane] = acc;
    __syncthreads();
    if (wave == 0)
        gpart[(size_t)blockIdx.x * HD + lane] =
            red[0][lane] + red[1][lane] + red[2][lane] + red[3][lane];
}

__global__ void global_head(const float* __restrict__ gpart, const int* __restrict__ start,
                            const float* __restrict__ g1W, const float* __restrict__ g1b,
                            const float* __restrict__ g2W, const float* __restrict__ g2b,
                            float* __restrict__ out) {
    __shared__ float rS[HD];
    int g = blockIdx.x;
    int j = threadIdx.x;  // 64
    int cnt = start[g + 1] - start[g];
    float inv = 1.f / fmaxf((float)cnt, 1.f);
    rS[j] = (gpart[(size_t)(4 * g + 0) * HD + j] + gpart[(size_t)(4 * g + 1) * HD + j] +
             gpart[(size_t)(4 * g + 2) * HD + j] + gpart[(size_t)(4 * g + 3) * HD + j]) * inv;
    __syncthreads();
    float a = g1b[j];
    #pragma unroll
    for (int k = 0; k < HD; ++k) a = fmaf(rS[k], g1W[k * HD + j], a);
    a = fmaxf(a, 0.f);
    float o0 = a * g2W[j * GT + 0];
    float o1 = a * g2W[j * GT + 1];
    float o2 = a * g2W[j * GT + 2];
    float o3 = a * g2W[j * GT + 3];
    #pragma unroll
    for (int off = 1; off < 64; off <<= 1) {
        o0 += __shfl_xor(o0, off, 64);
        o1 += __shfl_xor(o1, off, 64);
        o2 += __shfl_xor(o2, off, 64);
        o3 += __shfl_xor(o3, off, 64);
    }
    if (j == 0) {
        out[g * GT + 0] = o0 + g2b[0];
        out[g * GT + 1] = o1 + g2b[1];
        out[g * GT + 2] = o2 + g2b[2];
        out[g * GT + 3] = o3 + g2b[3];
    }
}

// ---------------- launch ----------------

extern "C" void kernel_launch(void* const* d_in, const int* in_sizes, int n_in,
                              void* d_out, int out_size, void* d_ws, size_t ws_size,
                              hipStream_t stream) {
    const float* x    = (const float*)d_in[0];
    const int*   ei   = (const int*)d_in[1];
    const int*   batch= (const int*)d_in[2];
    const float* encW = (const float*)d_in[3];
    const float* encb = (const float*)d_in[4];
    const float* convW= (const float*)d_in[5];
    const float* convb= (const float*)d_in[6];
    const float* nodeW= (const float*)d_in[7];
    const float* nodeb= (const float*)d_in[8];
    const float* g1W  = (const float*)d_in[9];
    const float* g1b  = (const float*)d_in[10];
    const float* g2W  = (const float*)d_in[11];
    const float* g2b  = (const float*)d_in[12];
    float* out = (float*)d_out;

    const int N = N_NODES, E = N_EDGES;

    char* ws = (char*)d_ws;
    size_t off = 0;
    auto alloc = [&](size_t bytes) -> void* {
        void* p = ws + off;
        off += (bytes + 255) & ~(size_t)255;
        return p;
    };
    // zeroed region first (one small memset): cnt only
    int*   cnt    = (int*)alloc((size_t)N * 4);
    size_t zbytes = off;
    // rest (all fully written before read)
    int*   rank   = (int*)alloc((size_t)E * 4);
    int*   offs   = (int*)alloc((size_t)N * 4);
    int*   cnt16  = (int*)alloc((size_t)N * 4);
    float* dis    = (float*)alloc((size_t)N * 4);
    int*   bsums  = (int*)alloc(256 * 4);
    int*   start  = (int*)alloc((size_t)(N_GRAPHS + 1) * 4);
    float* gpart  = (float*)alloc((size_t)N_GRAPHS * 4 * HD * 4);
    uint4* wfrag  = (uint4*)alloc((size_t)NLAYERS * 512 * 16);
    int*   srcs   = (int*)alloc((size_t)RECS_CAP * 4);
    __half* ht1   = (__half*)alloc((size_t)(N + 1) * HD * 2);  // +1 pad row
    __half* ht2   = (__half*)alloc((size_t)(N + 1) * HD * 2);

    hipMemsetAsync(d_ws, 0, zbytes, stream);

    const int B = 256;
    count_edges<<<(E + B - 1) / B, B, 0, stream>>>(ei + E, cnt, rank, E);
    compute_dis<<<(N + B - 1) / B, B, 0, stream>>>(cnt, dis, cnt16, N);
    int nb1 = (N + 1023) / 1024;
    scan1<<<nb1, 256, 0, stream>>>(cnt16, offs, bsums, N);
    scan2<<<1, 256, 0, stream>>>(bsums, nb1);
    scan3<<<(N + B - 1) / B, B, 0, stream>>>(offs, bsums, N);
    fill_kernel<<<(E + B - 1) / B, B, 0, stream>>>(ei, ei + E, rank, offs, srcs, E);
    pad_fill<<<(N + B - 1) / B, B, 0, stream>>>(cnt, cnt16, offs, srcs, N);
    zero_pad_row<<<1, 256, 0, stream>>>(ht1, ht2);
    graph_bounds<<<(N + B - 1) / B, B, 0, stream>>>(batch, start, N);
    prepack_W<<<NLAYERS, 256, 0, stream>>>(convW, wfrag);

    encoder_kernel<<<(N + 15) / 16, 256, 0, stream>>>(x, encW, encb, dis, ht1, N);

    __half* hin = ht1;
    __half* hot = ht2;
    for (int i = 0; i < NLAYERS; ++i) {
        layer_kernel<<<N / 16, 256, 0, stream>>>(hin, offs, cnt16, (const int4*)srcs, dis,
                                                 wfrag + (size_t)i * 512,
                                                 convb + (size_t)i * HD,
                                                 hot, (i < NLAYERS - 1) ? 1 : 0);
        __half* t = hin; hin = hot; hot = t;
    }

    node_head16<<<(N + 31) / 32, 256, 0, stream>>>(hin, nodeW, nodeb, out, N);
    pool16<<<N_GRAPHS * 4, 256, 0, stream>>>(hin, start, gpart);
    global_head<<<N_GRAPHS, 64, 0, stream>>>(gpart, start, g1W, g1b, g2W, g2b, out + (size_t)N * NT);
}

// Round 11
// 295.999 us; speedup vs baseline: 1.6427x; 1.0805x over previous
//
#include <hip/hip_runtime.h>
#include <hip/hip_fp16.h>

#define N_NODES 100000
#define N_EDGES 1250000
#define N_GRAPHS 64
#define F_INN 29
#define HD 64
#define NT 6
#define GT 4
#define NLAYERS 4
#define RECS_CAP 3000000  // >= E + 15*N worst-case padded size
#define NBLK 1563         // ceil(N_NODES / 64) dest-buckets

typedef __attribute__((ext_vector_type(8))) _Float16 f16x8;
typedef __attribute__((ext_vector_type(4))) float f32x4;

// ---------------- CSR construction ----------------

__global__ void count_edges(const int* __restrict__ col, int* __restrict__ cnt,
                            int* __restrict__ rank, int E) {
    int e = blockIdx.x * blockDim.x + threadIdx.x;
    if (e < E) rank[e] = atomicAdd(&cnt[col[e]], 1);
}

__global__ void compute_dis(const int* __restrict__ cnt, float* __restrict__ dis,
                            int* __restrict__ cnt16, int n) {
    int i = blockIdx.x * blockDim.x + threadIdx.x;
    if (i < n) {
        int c = cnt[i];
        dis[i] = rsqrtf((float)(c + 1));
        cnt16[i] = (c + 15) & ~15;
    }
}

__global__ void scan1(const int* __restrict__ in, int* __restrict__ out,
                      int* __restrict__ bsums, int n) {
    __shared__ int wsum[4];
    int tid = threadIdx.x;
    int base = blockIdx.x * 1024 + tid * 4;
    int v0 = (base + 0 < n) ? in[base + 0] : 0;
    int v1 = (base + 1 < n) ? in[base + 1] : 0;
    int v2 = (base + 2 < n) ? in[base + 2] : 0;
    int v3 = (base + 3 < n) ? in[base + 3] : 0;
    int tsum = v0 + v1 + v2 + v3;
    int incl = tsum;
    int lane = tid & 63;
    #pragma unroll
    for (int off = 1; off < 64; off <<= 1) {
        int t = __shfl_up(incl, (unsigned)off, 64);
        if (lane >= off) incl += t;
    }
    if (lane == 63) wsum[tid >> 6] = incl;
    __syncthreads();
    int woff = 0;
    for (int w = 0; w < (tid >> 6); ++w) woff += wsum[w];
    int run = woff + incl - tsum;
    if (base + 0 < n) out[base + 0] = run; run += v0;
    if (base + 1 < n) out[base + 1] = run; run += v1;
    if (base + 2 < n) out[base + 2] = run; run += v2;
    if (base + 3 < n) out[base + 3] = run;
    if (tid == 255) bsums[blockIdx.x] = woff + incl;
}

__global__ void scan2(int* __restrict__ bsums, int nb) {
    __shared__ int s[256];
    int tid = threadIdx.x;
    int v = (tid < nb) ? bsums[tid] : 0;
    s[tid] = v;
    __syncthreads();
    #pragma unroll
    for (int off = 1; off < 256; off <<= 1) {
        int t = (tid >= off) ? s[tid - off] : 0;
        __syncthreads();
        s[tid] += t;
        __syncthreads();
    }
    if (tid < nb) bsums[tid] = s[tid] - v;
}

__global__ void scan3(int* __restrict__ out, const int* __restrict__ bsums, int n) {
    int i = blockIdx.x * blockDim.x + threadIdx.x;
    if (i < n) out[i] += bsums[i >> 10];
}

__global__ void fill_kernel(const int* __restrict__ row, const int* __restrict__ col,
                            const int* __restrict__ rank, const int* __restrict__ offs,
                            int* __restrict__ srcs, int E) {
    int e = blockIdx.x * blockDim.x + threadIdx.x;
    if (e >= E) return;
    srcs[offs[col[e]] + rank[e]] = row[e];
}

__global__ void pad_fill(const int* __restrict__ cnt, const int* __restrict__ cnt16,
                         const int* __restrict__ offs, int* __restrict__ srcs, int n) {
    int i = blockIdx.x * blockDim.x + threadIdx.x;
    if (i >= n) return;
    int base = offs[i];
    int e0 = base + cnt[i];
    int e1 = base + cnt16[i];
    for (int p = e0; p < e1; ++p) srcs[p] = N_NODES;  // pad -> zero row
}

__global__ void zero_pad_row(__half* __restrict__ h1, __half* __restrict__ h2) {
    int t = threadIdx.x;
    if (t < HD) h1[(size_t)N_NODES * HD + t] = __float2half_rn(0.f);
    else if (t < 2 * HD) h2[(size_t)N_NODES * HD + (t - HD)] = __float2half_rn(0.f);
}

__global__ void graph_bounds(const int* __restrict__ batch, int* __restrict__ start, int n) {
    int i = blockIdx.x * blockDim.x + threadIdx.x;
    if (i >= n) return;
    int b = batch[i];
    if (i == 0) {
        for (int g = 0; g <= b; ++g) start[g] = 0;
    } else {
        int pb = batch[i - 1];
        if (pb != b) for (int g = pb + 1; g <= b; ++g) start[g] = i;
    }
    if (i == n - 1) {
        for (int g = b + 1; g <= N_GRAPHS; ++g) start[g] = n;
    }
}

// Pre-pack conv weights into MFMA B-fragment order (fp16), 512 x 16B slots/layer.
// slot s: jt=s>>7, ks=(s>>6)&1, l=s&63 -> halfs i=0..7 = W[ks*32+(l>>4)*8+i][jt*16+(l&15)]
__global__ void prepack_W(const float* __restrict__ convW, uint4* __restrict__ wfrag) {
    int layer = blockIdx.x;
    const float* W = convW + (size_t)layer * HD * HD;
    uint4* out = wfrag + (size_t)layer * 512;
    for (int s = threadIdx.x; s < 512; s += 256) {
        int jt = s >> 7, ks = (s >> 6) & 1, l = s & 63;
        int j = jt * 16 + (l & 15);
        int k0 = ks * 32 + (l >> 4) * 8;
        __align__(16) __half hh[8];
        #pragma unroll
        for (int i = 0; i < 8; ++i) hh[i] = __float2half_rn(W[(size_t)(k0 + i) * HD + j]);
        out[s] = *reinterpret_cast<const uint4*>(hh);
    }
}

// ---------------- dense layers ----------------

// ht = fp16( dis * relu(x @ encW + encb) )
__global__ void encoder_kernel(const float* __restrict__ x, const float* __restrict__ W,
                               const float* __restrict__ b, const float* __restrict__ dis,
                               __half* __restrict__ ht, int n) {
    __shared__ float Ws[F_INN * HD];
    __shared__ float bs[HD];
    __shared__ float xs[16 * F_INN];
    int tid = threadIdx.x;
    for (int i = tid; i < F_INN * HD; i += 256) Ws[i] = W[i];
    if (tid < HD) bs[tid] = b[tid];
    int n0 = blockIdx.x * 16;
    for (int i = tid; i < 16 * F_INN; i += 256) {
        int nn = n0 + i / F_INN;
        xs[i] = (nn < n) ? x[(size_t)nn * F_INN + (i % F_INN)] : 0.f;
    }
    __syncthreads();
    #pragma unroll
    for (int it = 0; it < 4; ++it) {
        int l = it * 4 + (tid >> 6);
        int j = tid & 63;
        int nn = n0 + l;
        if (nn < n) {
            float a = bs[j];
            #pragma unroll
            for (int k = 0; k < F_INN; ++k) a = fmaf(xs[l * F_INN + k], Ws[k * HD + j], a);
            ht[(size_t)nn * HD + j] = __float2half_rn(dis[nn] * fmaxf(a, 0.f));
        }
    }
}

__device__ __forceinline__ float4 cvtrow(uint2 u) {
    float2 a = __half22float2(*reinterpret_cast<const __half2*>(&u.x));
    float2 b = __half22float2(*reinterpret_cast<const __half2*>(&u.y));
    return make_float4(a.x, a.y, b.x, b.y);
}

#define ROW16(src) (*reinterpret_cast<const uint2*>(&ht[(size_t)(src) * HD + fh]))
#define H2(u) (*reinterpret_cast<const __half2*>(&(u)))
// 4-row fp16 tree -> fp32 accumulate (round-9 numerics)
#define ACC4T(r0, r1, r2, r3) { \
    __half2 ax = __hadd2(__hadd2(H2(r0.x), H2(r1.x)), __hadd2(H2(r2.x), H2(r3.x))); \
    __half2 ay = __hadd2(__hadd2(H2(r0.y), H2(r1.y)), __hadd2(H2(r2.y), H2(r3.y))); \
    float2 fx = __half22float2(ax); \
    float2 fy = __half22float2(ay); \
    acc.x += fx.x; acc.y += fx.y; acc.z += fy.x; acc.w += fy.y; }

// Bucketed GCN layer: block owns 64 consecutive dests; quarter-wave q of wave w
// walks the flat CSR slot range of its 4 dests (each dest range is a multiple of
// 16 slots, so aligned 16-slot groups never straddle dests). Per group: 4 int4
// index loads + 16 row loads (fp16, 8B/lane) -> 4-row fp16 trees -> fp32 acc.
// Dest boundary => add SELF row H~[dest], flush acc (fp16) into aggS row.
// Then block-cooperative MFMA: wave = j-tile, 4 node-tiles x 2 k-steps.
__global__ void layer_kernel(const __half* __restrict__ ht,
                             const int* __restrict__ offs, const int* __restrict__ cnt16,
                             const int4* __restrict__ srcs4,
                             const float* __restrict__ dis,
                             const uint4* __restrict__ wfragL, const float* __restrict__ bias,
                             __half* __restrict__ hout, int scaleOut) {
    __shared__ uint4 WfS[512];        // 8KB B-fragments
    __shared__ __half aggS[64 * 72];  // 64 agg rows, stride 72 halfs (bank-safe)
    __shared__ int offsS[64];
    __shared__ int cntS[64];
    __shared__ float disS[64];
    int tid = threadIdx.x;
    int b = blockIdx.x;
    WfS[tid] = wfragL[tid];
    WfS[tid + 256] = wfragL[tid + 256];
    if (tid < 64) {
        int d = b * 64 + tid;
        if (d < N_NODES) {
            offsS[tid] = offs[d];
            cntS[tid] = cnt16[d];
            disS[tid] = dis[d];
        } else {
            offsS[tid] = offs[N_NODES - 1] + cnt16[N_NODES - 1];  // collapsed empty range
            cntS[tid] = 0;
            disS[tid] = 0.f;
        }
    }
    __syncthreads();

    int wave = tid >> 6;
    int lane = tid & 63;
    int q = lane >> 4;
    int fh = (lane & 15) * 4;  // feature offset in halfs

    // quarter q handles local dests [l0, l0+4)
    int l0 = wave * 16 + q * 4;
    int s = offsS[l0];
    int e = offsS[l0 + 3] + cntS[l0 + 3];
    int dcur = l0;
    int nb = offsS[l0] + cntS[l0];
    float4 acc = {0.f, 0.f, 0.f, 0.f};

    // flush: add SELF row of dest dcur, store fp16 agg row, reset acc
    auto flush = [&](int d) {
        int nodeD = b * 64 + d;
        float4 sf = cvtrow(*reinterpret_cast<const uint2*>(
            &ht[(size_t)min(nodeD, N_NODES) * HD + fh]));
        acc.x += sf.x; acc.y += sf.y; acc.z += sf.z; acc.w += sf.w;
        __half2 h0 = __floats2half2_rn(acc.x, acc.y);
        __half2 h1 = __floats2half2_rn(acc.z, acc.w);
        uint2 w;
        w.x = *(unsigned*)&h0;
        w.y = *(unsigned*)&h1;
        *reinterpret_cast<uint2*>(&aggS[d * 72 + fh]) = w;
        acc = make_float4(0.f, 0.f, 0.f, 0.f);
    };

    for (int p = s; p < e; p += 16) {
        while (p >= nb) {  // finished dest(s), incl zero-edge ones
            flush(dcur);
            ++dcur;
            nb = offsS[dcur] + cntS[dcur];
        }
        int base = p >> 2;
        int4 e0 = srcs4[base + 0];
        int4 e1 = srcs4[base + 1];
        int4 e2 = srcs4[base + 2];
        int4 e3 = srcs4[base + 3];
        uint2 r0 = ROW16(e0.x), r1 = ROW16(e0.y), r2 = ROW16(e0.z), r3 = ROW16(e0.w);
        uint2 r4 = ROW16(e1.x), r5 = ROW16(e1.y), r6 = ROW16(e1.z), r7 = ROW16(e1.w);
        uint2 r8 = ROW16(e2.x), r9 = ROW16(e2.y), r10 = ROW16(e2.z), r11 = ROW16(e2.w);
        uint2 r12 = ROW16(e3.x), r13 = ROW16(e3.y), r14 = ROW16(e3.z), r15 = ROW16(e3.w);
        ACC4T(r0, r1, r2, r3);
        ACC4T(r4, r5, r6, r7);
        ACC4T(r8, r9, r10, r11);
        ACC4T(r12, r13, r14, r15);
    }
    // flush remaining dests (last active + any trailing empties)
    while (dcur <= l0 + 3) {
        flush(dcur);
        ++dcur;
    }
    __syncthreads();

    // MFMA: wave = j-tile; A row = nt*16 + (lane&15), k = ks*32 + (lane>>4)*8 + i
    f32x4 c0 = {0.f, 0.f, 0.f, 0.f}, c1 = c0, c2 = c0, c3 = c0;
    #pragma unroll
    for (int ks = 0; ks < 2; ++ks) {
        f16x8 bf = *reinterpret_cast<const f16x8*>(&WfS[(wave * 2 + ks) * 64 + lane]);
        f16x8 a0 = *reinterpret_cast<const f16x8*>(&aggS[(0 * 16 + (lane & 15)) * 72 + ks * 32 + (lane >> 4) * 8]);
        c0 = __builtin_amdgcn_mfma_f32_16x16x32_f16(a0, bf, c0, 0, 0, 0);
        f16x8 a1 = *reinterpret_cast<const f16x8*>(&aggS[(1 * 16 + (lane & 15)) * 72 + ks * 32 + (lane >> 4) * 8]);
        c1 = __builtin_amdgcn_mfma_f32_16x16x32_f16(a1, bf, c1, 0, 0, 0);
        f16x8 a2 = *reinterpret_cast<const f16x8*>(&aggS[(2 * 16 + (lane & 15)) * 72 + ks * 32 + (lane >> 4) * 8]);
        c2 = __builtin_amdgcn_mfma_f32_16x16x32_f16(a2, bf, c2, 0, 0, 0);
        f16x8 a3 = *reinterpret_cast<const f16x8*>(&aggS[(3 * 16 + (lane & 15)) * 72 + ks * 32 + (lane >> 4) * 8]);
        c3 = __builtin_amdgcn_mfma_f32_16x16x32_f16(a3, bf, c3, 0, 0, 0);
    }
    // epilogue: D col = lane&15 (within j-tile), row = (lane>>4)*4 + i (within node-tile)
    int j = wave * 16 + (lane & 15);
    float bj = bias[j];
    #pragma unroll
    for (int nt = 0; nt < 4; ++nt) {
        f32x4 c = (nt == 0) ? c0 : (nt == 1) ? c1 : (nt == 2) ? c2 : c3;
        #pragma unroll
        for (int i = 0; i < 4; ++i) {
            int rl = nt * 16 + (lane >> 4) * 4 + i;
            int node = b * 64 + rl;
            if (node < N_NODES) {
                float dn = disS[rl];
                float o = fmaxf(fmaf(dn, c[i], bj), 0.f);
                if (scaleOut) o *= dn;
                hout[(size_t)node * HD + j] = __float2half_rn(o);
            }
        }
    }
}

// pred_node = h @ nodeW + nodeb from fp16 h (streaming)
__global__ void node_head16(const __half* __restrict__ h, const float* __restrict__ W,
                            const float* __restrict__ b, float* __restrict__ out, int n) {
    __shared__ float Ws[HD * NT];
    __shared__ float bs[NT];
    __shared__ float hs[32 * 65];
    int tid = threadIdx.x;
    for (int i = tid; i < HD * NT; i += 256) Ws[i] = W[i];
    if (tid < NT) bs[tid] = b[tid];
    int n0 = blockIdx.x * 32;
    const unsigned* hrow = reinterpret_cast<const unsigned*>(&h[(size_t)n0 * HD]);
    for (int i = tid; i < 32 * HD / 2; i += 256) {
        unsigned u = hrow[i];
        float2 f = __half22float2(*reinterpret_cast<const __half2*>(&u));
        int el = i * 2;
        int row = el >> 6, colc = el & 63;
        hs[row * 65 + colc] = f.x;
        hs[row * 65 + colc + 1] = f.y;
    }
    __syncthreads();
    int l = tid >> 3, t = tid & 7;
    int nn = n0 + l;
    if (nn < n && t < NT) {
        float a = bs[t];
        #pragma unroll
        for (int k = 0; k < HD; ++k) a = fmaf(hs[l * 65 + k], Ws[k * NT + t], a);
        out[(size_t)nn * NT + t] = a;
    }
}

// atomic-free pooling from fp16 h: 4 blocks per graph
__global__ void pool16(const __half* __restrict__ h, const int* __restrict__ start,
                       float* __restrict__ gpart) {
    __shared__ float red[4][HD];
    int g = blockIdx.x >> 2, q = blockIdx.x & 3;
    int s0 = start[g], e0 = start[g + 1];
    int len = e0 - s0;
    int qs = s0 + (len * q) / 4;
    int qe = s0 + (len * (q + 1)) / 4;
    int wave = threadIdx.x >> 6, lane = threadIdx.x & 63;
    float acc = 0.f;
    for (int r = qs + wave; r < qe; r += 4) acc += __half2float(h[(size_t)r * HD + lane]);
    red[wave][lane] = acc;
    __syncthreads();
    if (wave == 0)
        gpart[(size_t)blockIdx.x * HD + lane] =
            red[0][lane] + red[1][lane] + red[2][lane] + red[3][lane];
}

__global__ void global_head(const float* __restrict__ gpart, const int* __restrict__ start,
                            const float* __restrict__ g1W, const float* __restrict__ g1b,
                            const float* __restrict__ g2W, const float* __restrict__ g2b,
                            float* __restrict__ out) {
    __shared__ float rS[HD];
    int g = blockIdx.x;
    int j = threadIdx.x;  // 64
    int cnt = start[g + 1] - start[g];
    float inv = 1.f / fmaxf((float)cnt, 1.f);
    rS[j] = (gpart[(size_t)(4 * g + 0) * HD + j] + gpart[(size_t)(4 * g + 1) * HD + j] +
             gpart[(size_t)(4 * g + 2) * HD + j] + gpart[(size_t)(4 * g + 3) * HD + j]) * inv;
    __syncthreads();
    float a = g1b[j];
    #pragma unroll
    for (int k = 0; k < HD; ++k) a = fmaf(rS[k], g1W[k * HD + j], a);
    a = fmaxf(a, 0.f);
    float o0 = a * g2W[j * GT + 0];
    float o1 = a * g2W[j * GT + 1];
    float o2 = a * g2W[j * GT + 2];
    float o3 = a * g2W[j * GT + 3];
    #pragma unroll
    for (int off = 1; off < 64; off <<= 1) {
        o0 += __shfl_xor(o0, off, 64);
        o1 += __shfl_xor(o1, off, 64);
        o2 += __shfl_xor(o2, off, 64);
        o3 += __shfl_xor(o3, off, 64);
    }
    if (j == 0) {
        out[g * GT + 0] = o0 + g2b[0];
        out[g * GT + 1] = o1 + g2b[1];
        out[g * GT + 2] = o2 + g2b[2];
        out[g * GT + 3] = o3 + g2b[3];
    }
}

// ---------------- launch ----------------

extern "C" void kernel_launch(void* const* d_in, const int* in_sizes, int n_in,
                              void* d_out, int out_size, void* d_ws, size_t ws_size,
                              hipStream_t stream) {
    const float* x    = (const float*)d_in[0];
    const int*   ei   = (const int*)d_in[1];
    const int*   batch= (const int*)d_in[2];
    const float* encW = (const float*)d_in[3];
    const float* encb = (const float*)d_in[4];
    const float* convW= (const float*)d_in[5];
    const float* convb= (const float*)d_in[6];
    const float* nodeW= (const float*)d_in[7];
    const float* nodeb= (const float*)d_in[8];
    const float* g1W  = (const float*)d_in[9];
    const float* g1b  = (const float*)d_in[10];
    const float* g2W  = (const float*)d_in[11];
    const float* g2b  = (const float*)d_in[12];
    float* out = (float*)d_out;

    const int N = N_NODES, E = N_EDGES;

    char* ws = (char*)d_ws;
    size_t off = 0;
    auto alloc = [&](size_t bytes) -> void* {
        void* p = ws + off;
        off += (bytes + 255) & ~(size_t)255;
        return p;
    };
    // zeroed region first (one small memset): cnt only
    int*   cnt    = (int*)alloc((size_t)N * 4);
    size_t zbytes = off;
    // rest (all fully written before read)
    int*   rank   = (int*)alloc((size_t)E * 4);
    int*   offs   = (int*)alloc((size_t)N * 4);
    int*   cnt16  = (int*)alloc((size_t)N * 4);
    float* dis    = (float*)alloc((size_t)N * 4);
    int*   bsums  = (int*)alloc(256 * 4);
    int*   start  = (int*)alloc((size_t)(N_GRAPHS + 1) * 4);
    float* gpart  = (float*)alloc((size_t)N_GRAPHS * 4 * HD * 4);
    uint4* wfrag  = (uint4*)alloc((size_t)NLAYERS * 512 * 16);
    int*   srcs   = (int*)alloc((size_t)RECS_CAP * 4);
    __half* ht1   = (__half*)alloc((size_t)(N + 1) * HD * 2);  // +1 pad row
    __half* ht2   = (__half*)alloc((size_t)(N + 1) * HD * 2);

    hipMemsetAsync(d_ws, 0, zbytes, stream);

    const int B = 256;
    count_edges<<<(E + B - 1) / B, B, 0, stream>>>(ei + E, cnt, rank, E);
    compute_dis<<<(N + B - 1) / B, B, 0, stream>>>(cnt, dis, cnt16, N);
    int nb1 = (N + 1023) / 1024;
    scan1<<<nb1, 256, 0, stream>>>(cnt16, offs, bsums, N);
    scan2<<<1, 256, 0, stream>>>(bsums, nb1);
    scan3<<<(N + B - 1) / B, B, 0, stream>>>(offs, bsums, N);
    fill_kernel<<<(E + B - 1) / B, B, 0, stream>>>(ei, ei + E, rank, offs, srcs, E);
    pad_fill<<<(N + B - 1) / B, B, 0, stream>>>(cnt, cnt16, offs, srcs, N);
    zero_pad_row<<<1, 256, 0, stream>>>(ht1, ht2);
    graph_bounds<<<(N + B - 1) / B, B, 0, stream>>>(batch, start, N);
    prepack_W<<<NLAYERS, 256, 0, stream>>>(convW, wfrag);

    encoder_kernel<<<(N + 15) / 16, 256, 0, stream>>>(x, encW, encb, dis, ht1, N);

    __half* hin = ht1;
    __half* hot = ht2;
    for (int i = 0; i < NLAYERS; ++i) {
        layer_kernel<<<NBLK, 256, 0, stream>>>(hin, offs, cnt16, (const int4*)srcs, dis,
                                               wfrag + (size_t)i * 512,
                                               convb + (size_t)i * HD,
                                               hot, (i < NLAYERS - 1) ? 1 : 0);
        __half* t = hin; hin = hot; hot = t;
    }

    node_head16<<<(N + 31) / 32, 256, 0, stream>>>(hin, nodeW, nodeb, out, N);
    pool16<<<N_GRAPHS * 4, 256, 0, stream>>>(hin, start, gpart);
    global_head<<<N_GRAPHS, 64, 0, stream>>>(gpart, start, g1W, g1b, g2W, g2b, out + (size_t)N * NT);
}

// Round 12
// 256.157 us; speedup vs baseline: 1.8982x; 1.1555x over previous
//
#include <hip/hip_runtime.h>
#include <hip/hip_fp16.h>

#define N_NODES 100000
#define N_EDGES 1250000
#define N_GRAPHS 64
#define F_INN 29
#define HD 64
#define NT 6
#define GT 4
#define NLAYERS 4
#define RECS_CAP 3000000  // >= E + 15*N worst-case padded size
#define NBLK 1563         // ceil(N_NODES / 64) dest-buckets (layer)
#define NBUK 782          // ceil(N_NODES / 128) CSR-build buckets
#define HGRID 256         // blocks in hist/scatter (edge partition)

typedef __attribute__((ext_vector_type(8))) _Float16 f16x8;
typedef __attribute__((ext_vector_type(4))) float f32x4;

// ---------------- atomic-free CSR construction ----------------

// K1: per-block LDS histogram over node>>7 buckets, transposed write
__global__ void hist1(const int* __restrict__ col, int* __restrict__ ghistT, int E) {
    __shared__ int lh[NBUK];
    int tid = threadIdx.x, b = blockIdx.x;
    for (int i = tid; i < NBUK; i += 256) lh[i] = 0;
    __syncthreads();
    for (int e = b * 256 + tid; e < E; e += HGRID * 256) atomicAdd(&lh[col[e] >> 7], 1);
    __syncthreads();
    for (int i = tid; i < NBUK; i += 256) ghistT[i * 256 + b] = lh[i];
}

// K2: per-bucket exclusive scan over the 256 block counts; tot[k] = bucket total
__global__ void hist_colscan(int* __restrict__ ghistT, int* __restrict__ tot) {
    __shared__ int wsum[4];
    int k = blockIdx.x, tid = threadIdx.x;
    int v = ghistT[k * 256 + tid];
    int incl = v;
    int lane = tid & 63;
    #pragma unroll
    for (int off = 1; off < 64; off <<= 1) {
        int t = __shfl_up(incl, (unsigned)off, 64);
        if (lane >= off) incl += t;
    }
    if (lane == 63) wsum[tid >> 6] = incl;
    __syncthreads();
    int woff = 0;
    for (int w = 0; w < (tid >> 6); ++w) woff += wsum[w];
    ghistT[k * 256 + tid] = woff + incl - v;  // exclusive
    if (tid == 255) tot[k] = woff + incl;
}

// generic exclusive scan (1024/block) — also used for boff (1 block) and offs
__global__ void scan1(const int* __restrict__ in, int* __restrict__ out,
                      int* __restrict__ bsums, int n) {
    __shared__ int wsum[4];
    int tid = threadIdx.x;
    int base = blockIdx.x * 1024 + tid * 4;
    int v0 = (base + 0 < n) ? in[base + 0] : 0;
    int v1 = (base + 1 < n) ? in[base + 1] : 0;
    int v2 = (base + 2 < n) ? in[base + 2] : 0;
    int v3 = (base + 3 < n) ? in[base + 3] : 0;
    int tsum = v0 + v1 + v2 + v3;
    int incl = tsum;
    int lane = tid & 63;
    #pragma unroll
    for (int off = 1; off < 64; off <<= 1) {
        int t = __shfl_up(incl, (unsigned)off, 64);
        if (lane >= off) incl += t;
    }
    if (lane == 63) wsum[tid >> 6] = incl;
    __syncthreads();
    int woff = 0;
    for (int w = 0; w < (tid >> 6); ++w) woff += wsum[w];
    int run = woff + incl - tsum;
    if (base + 0 < n) out[base + 0] = run; run += v0;
    if (base + 1 < n) out[base + 1] = run; run += v1;
    if (base + 2 < n) out[base + 2] = run; run += v2;
    if (base + 3 < n) out[base + 3] = run;
    if (tid == 255) bsums[blockIdx.x] = woff + incl;
}

__global__ void scan2(int* __restrict__ bsums, int nb) {
    __shared__ int s[256];
    int tid = threadIdx.x;
    int v = (tid < nb) ? bsums[tid] : 0;
    s[tid] = v;
    __syncthreads();
    #pragma unroll
    for (int off = 1; off < 256; off <<= 1) {
        int t = (tid >= off) ? s[tid - off] : 0;
        __syncthreads();
        s[tid] += t;
        __syncthreads();
    }
    if (tid < nb) bsums[tid] = s[tid] - v;
}

__global__ void scan3(int* __restrict__ out, const int* __restrict__ bsums, int n) {
    int i = blockIdx.x * blockDim.x + threadIdx.x;
    if (i < n) out[i] += bsums[i >> 10];
}

// K3: scatter edges into bucket segments (LDS cursors, packed row|local<<25)
__global__ void scatter_buckets(const int* __restrict__ row, const int* __restrict__ col,
                                const int* __restrict__ ghistT, const int* __restrict__ boff,
                                unsigned* __restrict__ bke, int E) {
    __shared__ int cur[NBUK];
    int tid = threadIdx.x, b = blockIdx.x;
    for (int i = tid; i < NBUK; i += 256) cur[i] = ghistT[i * 256 + b] + boff[i];
    __syncthreads();
    for (int e = b * 256 + tid; e < E; e += HGRID * 256) {
        int c = col[e];
        int pos = atomicAdd(&cur[c >> 7], 1);  // LDS atomic
        bke[pos] = (unsigned)row[e] | ((unsigned)(c & 127) << 25);
    }
}

// K4: per-bucket LDS count -> cnt16, dis (folds compute_dis)
__global__ void bucket_count(const unsigned* __restrict__ bke, const int* __restrict__ boff,
                             int* __restrict__ cnt16, float* __restrict__ dis, int E) {
    __shared__ int lc[128];
    int k = blockIdx.x, tid = threadIdx.x;
    if (tid < 128) lc[tid] = 0;
    __syncthreads();
    int s = boff[k];
    int t = (k == NBUK - 1) ? E : boff[k + 1];
    for (int i = s + tid; i < t; i += 256) atomicAdd(&lc[bke[i] >> 25], 1);  // LDS atomic
    __syncthreads();
    if (tid < 128) {
        int node = k * 128 + tid;
        if (node < N_NODES) {
            int c = lc[tid];
            cnt16[node] = (c + 15) & ~15;
            dis[node] = rsqrtf((float)(c + 1));
        }
    }
}

// K5: per-bucket fill of final CSR + pad slots (folds pad_fill)
__global__ void bucket_fill(const unsigned* __restrict__ bke, const int* __restrict__ boff,
                            const int* __restrict__ offs, int* __restrict__ srcs, int E) {
    __shared__ int offsL[128];
    __shared__ int cur[128];
    int k = blockIdx.x, tid = threadIdx.x;
    if (tid < 128) {
        int node = k * 128 + tid;
        offsL[tid] = (node < N_NODES) ? offs[node] : 0;
        cur[tid] = 0;
    }
    __syncthreads();
    int s = boff[k];
    int t = (k == NBUK - 1) ? E : boff[k + 1];
    for (int i = s + tid; i < t; i += 256) {
        unsigned u = bke[i];
        int l = u >> 25;
        int r = atomicAdd(&cur[l], 1);  // LDS atomic
        srcs[offsL[l] + r] = (int)(u & 0x01FFFFFFu);
    }
    __syncthreads();
    if (tid < 128) {
        int node = k * 128 + tid;
        if (node < N_NODES) {
            int c = cur[tid];
            int c16 = (c + 15) & ~15;
            int base = offsL[tid];
            for (int p = base + c; p < base + c16; ++p) srcs[p] = N_NODES;  // pad -> zero row
        }
    }
}

__global__ void zero_pad_row(__half* __restrict__ h1, __half* __restrict__ h2) {
    int t = threadIdx.x;
    if (t < HD) h1[(size_t)N_NODES * HD + t] = __float2half_rn(0.f);
    else if (t < 2 * HD) h2[(size_t)N_NODES * HD + (t - HD)] = __float2half_rn(0.f);
}

__global__ void graph_bounds(const int* __restrict__ batch, int* __restrict__ start, int n) {
    int i = blockIdx.x * blockDim.x + threadIdx.x;
    if (i >= n) return;
    int b = batch[i];
    if (i == 0) {
        for (int g = 0; g <= b; ++g) start[g] = 0;
    } else {
        int pb = batch[i - 1];
        if (pb != b) for (int g = pb + 1; g <= b; ++g) start[g] = i;
    }
    if (i == n - 1) {
        for (int g = b + 1; g <= N_GRAPHS; ++g) start[g] = n;
    }
}

// Pre-pack conv weights into MFMA B-fragment order (fp16), 512 x 16B slots/layer.
__global__ void prepack_W(const float* __restrict__ convW, uint4* __restrict__ wfrag) {
    int layer = blockIdx.x;
    const float* W = convW + (size_t)layer * HD * HD;
    uint4* out = wfrag + (size_t)layer * 512;
    for (int s = threadIdx.x; s < 512; s += 256) {
        int jt = s >> 7, ks = (s >> 6) & 1, l = s & 63;
        int j = jt * 16 + (l & 15);
        int k0 = ks * 32 + (l >> 4) * 8;
        __align__(16) __half hh[8];
        #pragma unroll
        for (int i = 0; i < 8; ++i) hh[i] = __float2half_rn(W[(size_t)(k0 + i) * HD + j]);
        out[s] = *reinterpret_cast<const uint4*>(hh);
    }
}

// ---------------- dense layers ----------------

// ht = fp16( dis * relu(x @ encW + encb) )
__global__ void encoder_kernel(const float* __restrict__ x, const float* __restrict__ W,
                               const float* __restrict__ b, const float* __restrict__ dis,
                               __half* __restrict__ ht, int n) {
    __shared__ float Ws[F_INN * HD];
    __shared__ float bs[HD];
    __shared__ float xs[16 * F_INN];
    int tid = threadIdx.x;
    for (int i = tid; i < F_INN * HD; i += 256) Ws[i] = W[i];
    if (tid < HD) bs[tid] = b[tid];
    int n0 = blockIdx.x * 16;
    for (int i = tid; i < 16 * F_INN; i += 256) {
        int nn = n0 + i / F_INN;
        xs[i] = (nn < n) ? x[(size_t)nn * F_INN + (i % F_INN)] : 0.f;
    }
    __syncthreads();
    #pragma unroll
    for (int it = 0; it < 4; ++it) {
        int l = it * 4 + (tid >> 6);
        int j = tid & 63;
        int nn = n0 + l;
        if (nn < n) {
            float a = bs[j];
            #pragma unroll
            for (int k = 0; k < F_INN; ++k) a = fmaf(xs[l * F_INN + k], Ws[k * HD + j], a);
            ht[(size_t)nn * HD + j] = __float2half_rn(dis[nn] * fmaxf(a, 0.f));
        }
    }
}

__device__ __forceinline__ float4 cvtrow(uint2 u) {
    float2 a = __half22float2(*reinterpret_cast<const __half2*>(&u.x));
    float2 b = __half22float2(*reinterpret_cast<const __half2*>(&u.y));
    return make_float4(a.x, a.y, b.x, b.y);
}

#define ROW16(src) (*reinterpret_cast<const uint2*>(&ht[(size_t)(src) * HD + fh]))
#define H2(u) (*reinterpret_cast<const __half2*>(&(u)))
// 4-row fp16 tree -> fp32 accumulate
#define ACC4T(r0, r1, r2, r3) { \
    __half2 ax = __hadd2(__hadd2(H2(r0.x), H2(r1.x)), __hadd2(H2(r2.x), H2(r3.x))); \
    __half2 ay = __hadd2(__hadd2(H2(r0.y), H2(r1.y)), __hadd2(H2(r2.y), H2(r3.y))); \
    float2 fx = __half22float2(ax); \
    float2 fy = __half22float2(ay); \
    acc.x += fx.x; acc.y += fx.y; acc.z += fy.x; acc.w += fy.y; }

// Bucketed GCN layer (round-11 kernel, unchanged): block owns 64 dests; quarter-wave
// walks 4 dests' padded CSR slots (16/group); self row added at flush; block-coop MFMA.
__global__ void layer_kernel(const __half* __restrict__ ht,
                             const int* __restrict__ offs, const int* __restrict__ cnt16,
                             const int4* __restrict__ srcs4,
                             const float* __restrict__ dis,
                             const uint4* __restrict__ wfragL, const float* __restrict__ bias,
                             __half* __restrict__ hout, int scaleOut) {
    __shared__ uint4 WfS[512];        // 8KB B-fragments
    __shared__ __half aggS[64 * 72];  // 64 agg rows, stride 72 halfs
    __shared__ int offsS[64];
    __shared__ int cntS[64];
    __shared__ float disS[64];
    int tid = threadIdx.x;
    int b = blockIdx.x;
    WfS[tid] = wfragL[tid];
    WfS[tid + 256] = wfragL[tid + 256];
    if (tid < 64) {
        int d = b * 64 + tid;
        if (d < N_NODES) {
            offsS[tid] = offs[d];
            cntS[tid] = cnt16[d];
            disS[tid] = dis[d];
        } else {
            offsS[tid] = offs[N_NODES - 1] + cnt16[N_NODES - 1];
            cntS[tid] = 0;
            disS[tid] = 0.f;
        }
    }
    __syncthreads();

    int wave = tid >> 6;
    int lane = tid & 63;
    int q = lane >> 4;
    int fh = (lane & 15) * 4;

    int l0 = wave * 16 + q * 4;
    int s = offsS[l0];
    int e = offsS[l0 + 3] + cntS[l0 + 3];
    int dcur = l0;
    int nb = offsS[l0] + cntS[l0];
    float4 acc = {0.f, 0.f, 0.f, 0.f};

    auto flush = [&](int d) {
        int nodeD = b * 64 + d;
        float4 sf = cvtrow(*reinterpret_cast<const uint2*>(
            &ht[(size_t)min(nodeD, N_NODES) * HD + fh]));
        acc.x += sf.x; acc.y += sf.y; acc.z += sf.z; acc.w += sf.w;
        __half2 h0 = __floats2half2_rn(acc.x, acc.y);
        __half2 h1 = __floats2half2_rn(acc.z, acc.w);
        uint2 w;
        w.x = *(unsigned*)&h0;
        w.y = *(unsigned*)&h1;
        *reinterpret_cast<uint2*>(&aggS[d * 72 + fh]) = w;
        acc = make_float4(0.f, 0.f, 0.f, 0.f);
    };

    for (int p = s; p < e; p += 16) {
        while (p >= nb) {
            flush(dcur);
            ++dcur;
            nb = offsS[dcur] + cntS[dcur];
        }
        int base = p >> 2;
        int4 e0 = srcs4[base + 0];
        int4 e1 = srcs4[base + 1];
        int4 e2 = srcs4[base + 2];
        int4 e3 = srcs4[base + 3];
        uint2 r0 = ROW16(e0.x), r1 = ROW16(e0.y), r2 = ROW16(e0.z), r3 = ROW16(e0.w);
        uint2 r4 = ROW16(e1.x), r5 = ROW16(e1.y), r6 = ROW16(e1.z), r7 = ROW16(e1.w);
        uint2 r8 = ROW16(e2.x), r9 = ROW16(e2.y), r10 = ROW16(e2.z), r11 = ROW16(e2.w);
        uint2 r12 = ROW16(e3.x), r13 = ROW16(e3.y), r14 = ROW16(e3.z), r15 = ROW16(e3.w);
        ACC4T(r0, r1, r2, r3);
        ACC4T(r4, r5, r6, r7);
        ACC4T(r8, r9, r10, r11);
        ACC4T(r12, r13, r14, r15);
    }
    while (dcur <= l0 + 3) {
        flush(dcur);
        ++dcur;
    }
    __syncthreads();

    f32x4 c0 = {0.f, 0.f, 0.f, 0.f}, c1 = c0, c2 = c0, c3 = c0;
    #pragma unroll
    for (int ks = 0; ks < 2; ++ks) {
        f16x8 bf = *reinterpret_cast<const f16x8*>(&WfS[(wave * 2 + ks) * 64 + lane]);
        f16x8 a0 = *reinterpret_cast<const f16x8*>(&aggS[(0 * 16 + (lane & 15)) * 72 + ks * 32 + (lane >> 4) * 8]);
        c0 = __builtin_amdgcn_mfma_f32_16x16x32_f16(a0, bf, c0, 0, 0, 0);
        f16x8 a1 = *reinterpret_cast<const f16x8*>(&aggS[(1 * 16 + (lane & 15)) * 72 + ks * 32 + (lane >> 4) * 8]);
        c1 = __builtin_amdgcn_mfma_f32_16x16x32_f16(a1, bf, c1, 0, 0, 0);
        f16x8 a2 = *reinterpret_cast<const f16x8*>(&aggS[(2 * 16 + (lane & 15)) * 72 + ks * 32 + (lane >> 4) * 8]);
        c2 = __builtin_amdgcn_mfma_f32_16x16x32_f16(a2, bf, c2, 0, 0, 0);
        f16x8 a3 = *reinterpret_cast<const f16x8*>(&aggS[(3 * 16 + (lane & 15)) * 72 + ks * 32 + (lane >> 4) * 8]);
        c3 = __builtin_amdgcn_mfma_f32_16x16x32_f16(a3, bf, c3, 0, 0, 0);
    }
    int j = wave * 16 + (lane & 15);
    float bj = bias[j];
    #pragma unroll
    for (int nt = 0; nt < 4; ++nt) {
        f32x4 c = (nt == 0) ? c0 : (nt == 1) ? c1 : (nt == 2) ? c2 : c3;
        #pragma unroll
        for (int i = 0; i < 4; ++i) {
            int rl = nt * 16 + (lane >> 4) * 4 + i;
            int node = b * 64 + rl;
            if (node < N_NODES) {
                float dn = disS[rl];
                float o = fmaxf(fmaf(dn, c[i], bj), 0.f);
                if (scaleOut) o *= dn;
                hout[(size_t)node * HD + j] = __float2half_rn(o);
            }
        }
    }
}

// pred_node = h @ nodeW + nodeb from fp16 h (streaming)
__global__ void node_head16(const __half* __restrict__ h, const float* __restrict__ W,
                            const float* __restrict__ b, float* __restrict__ out, int n) {
    __shared__ float Ws[HD * NT];
    __shared__ float bs[NT];
    __shared__ float hs[32 * 65];
    int tid = threadIdx.x;
    for (int i = tid; i < HD * NT; i += 256) Ws[i] = W[i];
    if (tid < NT) bs[tid] = b[tid];
    int n0 = blockIdx.x * 32;
    const unsigned* hrow = reinterpret_cast<const unsigned*>(&h[(size_t)n0 * HD]);
    for (int i = tid; i < 32 * HD / 2; i += 256) {
        unsigned u = hrow[i];
        float2 f = __half22float2(*reinterpret_cast<const __half2*>(&u));
        int el = i * 2;
        int row = el >> 6, colc = el & 63;
        hs[row * 65 + colc] = f.x;
        hs[row * 65 + colc + 1] = f.y;
    }
    __syncthreads();
    int l = tid >> 3, t = tid & 7;
    int nn = n0 + l;
    if (nn < n && t < NT) {
        float a = bs[t];
        #pragma unroll
        for (int k = 0; k < HD; ++k) a = fmaf(hs[l * 65 + k], Ws[k * NT + t], a);
        out[(size_t)nn * NT + t] = a;
    }
}

// atomic-free pooling from fp16 h: 4 blocks per graph
__global__ void pool16(const __half* __restrict__ h, const int* __restrict__ start,
                       float* __restrict__ gpart) {
    __shared__ float red[4][HD];
    int g = blockIdx.x >> 2, q = blockIdx.x & 3;
    int s0 = start[g], e0 = start[g + 1];
    int len = e0 - s0;
    int qs = s0 + (len * q) / 4;
    int qe = s0 + (len * (q + 1)) / 4;
    int wave = threadIdx.x >> 6, lane = threadIdx.x & 63;
    float acc = 0.f;
    for (int r = qs + wave; r < qe; r += 4) acc += __half2float(h[(size_t)r * HD + lane]);
    red[wave][lane] = acc;
    __syncthreads();
    if (wave == 0)
        gpart[(size_t)blockIdx.x * HD + lane] =
            red[0][lane] + red[1][lane] + red[2][lane] + red[3][lane];
}

__global__ void global_head(const float* __restrict__ gpart, const int* __restrict__ start,
                            const float* __restrict__ g1W, const float* __restrict__ g1b,
                            const float* __restrict__ g2W, const float* __restrict__ g2b,
                            float* __restrict__ out) {
    __shared__ float rS[HD];
    int g = blockIdx.x;
    int j = threadIdx.x;  // 64
    int cnt = start[g + 1] - start[g];
    float inv = 1.f / fmaxf((float)cnt, 1.f);
    rS[j] = (gpart[(size_t)(4 * g + 0) * HD + j] + gpart[(size_t)(4 * g + 1) * HD + j] +
             gpart[(size_t)(4 * g + 2) * HD + j] + gpart[(size_t)(4 * g + 3) * HD + j]) * inv;
    __syncthreads();
    float a = g1b[j];
    #pragma unroll
    for (int k = 0; k < HD; ++k) a = fmaf(rS[k], g1W[k * HD + j], a);
    a = fmaxf(a, 0.f);
    float o0 = a * g2W[j * GT + 0];
    float o1 = a * g2W[j * GT + 1];
    float o2 = a * g2W[j * GT + 2];
    float o3 = a * g2W[j * GT + 3];
    #pragma unroll
    for (int off = 1; off < 64; off <<= 1) {
        o0 += __shfl_xor(o0, off, 64);
        o1 += __shfl_xor(o1, off, 64);
        o2 += __shfl_xor(o2, off, 64);
        o3 += __shfl_xor(o3, off, 64);
    }
    if (j == 0) {
        out[g * GT + 0] = o0 + g2b[0];
        out[g * GT + 1] = o1 + g2b[1];
        out[g * GT + 2] = o2 + g2b[2];
        out[g * GT + 3] = o3 + g2b[3];
    }
}

// ---------------- launch ----------------

extern "C" void kernel_launch(void* const* d_in, const int* in_sizes, int n_in,
                              void* d_out, int out_size, void* d_ws, size_t ws_size,
                              hipStream_t stream) {
    const float* x    = (const float*)d_in[0];
    const int*   ei   = (const int*)d_in[1];
    const int*   batch= (const int*)d_in[2];
    const float* encW = (const float*)d_in[3];
    const float* encb = (const float*)d_in[4];
    const float* convW= (const float*)d_in[5];
    const float* convb= (const float*)d_in[6];
    const float* nodeW= (const float*)d_in[7];
    const float* nodeb= (const float*)d_in[8];
    const float* g1W  = (const float*)d_in[9];
    const float* g1b  = (const float*)d_in[10];
    const float* g2W  = (const float*)d_in[11];
    const float* g2b  = (const float*)d_in[12];
    float* out = (float*)d_out;

    const int N = N_NODES, E = N_EDGES;

    char* ws = (char*)d_ws;
    size_t off = 0;
    auto alloc = [&](size_t bytes) -> void* {
        void* p = ws + off;
        off += (bytes + 255) & ~(size_t)255;
        return p;
    };
    // all buffers fully written before read — no memset needed
    int*    ghistT = (int*)alloc((size_t)NBUK * 256 * 4);
    int*    tot    = (int*)alloc((size_t)NBUK * 4);
    int*    boff   = (int*)alloc((size_t)NBUK * 4);
    unsigned* bke  = (unsigned*)alloc((size_t)E * 4);
    int*    offs   = (int*)alloc((size_t)N * 4);
    int*    cnt16  = (int*)alloc((size_t)N * 4);
    float*  dis    = (float*)alloc((size_t)N * 4);
    int*    bsums  = (int*)alloc(256 * 4);
    int*    start  = (int*)alloc((size_t)(N_GRAPHS + 1) * 4);
    float*  gpart  = (float*)alloc((size_t)N_GRAPHS * 4 * HD * 4);
    uint4*  wfrag  = (uint4*)alloc((size_t)NLAYERS * 512 * 16);
    int*    srcs   = (int*)alloc((size_t)RECS_CAP * 4);
    __half* ht1    = (__half*)alloc((size_t)(N + 1) * HD * 2);  // +1 pad row
    __half* ht2    = (__half*)alloc((size_t)(N + 1) * HD * 2);

    const int B = 256;
    // atomic-free CSR build
    hist1<<<HGRID, 256, 0, stream>>>(ei + E, ghistT, E);
    hist_colscan<<<NBUK, 256, 0, stream>>>(ghistT, tot);
    scan1<<<1, 256, 0, stream>>>(tot, boff, bsums, NBUK);
    scatter_buckets<<<HGRID, 256, 0, stream>>>(ei, ei + E, ghistT, boff, bke, E);
    bucket_count<<<NBUK, 256, 0, stream>>>(bke, boff, cnt16, dis, E);
    int nb1 = (N + 1023) / 1024;
    scan1<<<nb1, 256, 0, stream>>>(cnt16, offs, bsums, N);
    scan2<<<1, 256, 0, stream>>>(bsums, nb1);
    scan3<<<(N + B - 1) / B, B, 0, stream>>>(offs, bsums, N);
    bucket_fill<<<NBUK, 256, 0, stream>>>(bke, boff, offs, srcs, E);
    zero_pad_row<<<1, 256, 0, stream>>>(ht1, ht2);
    graph_bounds<<<(N + B - 1) / B, B, 0, stream>>>(batch, start, N);
    prepack_W<<<NLAYERS, 256, 0, stream>>>(convW, wfrag);

    encoder_kernel<<<(N + 15) / 16, 256, 0, stream>>>(x, encW, encb, dis, ht1, N);

    __half* hin = ht1;
    __half* hot = ht2;
    for (int i = 0; i < NLAYERS; ++i) {
        layer_kernel<<<NBLK, 256, 0, stream>>>(hin, offs, cnt16, (const int4*)srcs, dis,
                                               wfrag + (size_t)i * 512,
                                               convb + (size_t)i * HD,
                                               hot, (i < NLAYERS - 1) ? 1 : 0);
        __half* t = hin; hin = hot; hot = t;
    }

    node_head16<<<(N + 31) / 32, 256, 0, stream>>>(hin, nodeW, nodeb, out, N);
    pool16<<<N_GRAPHS * 4, 256, 0, stream>>>(hin, start, gpart);
    global_head<<<N_GRAPHS, 64, 0, stream>>>(gpart, start, g1W, g1b, g2W, g2b, out + (size_t)N * NT);
}

// Round 13
// 233.434 us; speedup vs baseline: 2.0829x; 1.0973x over previous
//
#include <hip/hip_runtime.h>
#include <hip/hip_fp16.h>

#define N_NODES 100000
#define N_EDGES 1250000
#define N_GRAPHS 64
#define F_INN 29
#define HD 64
#define NT 6
#define GT 4
#define NLAYERS 4
#define RECS_CAP 3000000  // >= E + 15*N worst-case padded size
#define NBLK 1563         // ceil(N_NODES / 64) dest-buckets (layer)
#define NBUK 782          // ceil(N_NODES / 128) CSR-build buckets
#define HGRID 256         // blocks in hist/scatter (edge partition)
#define GB_BLOCKS 391     // ceil(N/256) graph_bounds sections
#define ENC_BLOCKS 6250   // N/16 encoder sections
#define NH_BLOCKS 3125    // ceil(N/32) node-head sections

typedef __attribute__((ext_vector_type(8))) _Float16 f16x8;
typedef __attribute__((ext_vector_type(4))) float f32x4;

// ---------------- fused build + misc kernel ----------------
// sections: [0,HGRID) hist; [HGRID,HGRID+4) prepack_W; HGRID+4 zero pad rows;
// [HGRID+5, HGRID+5+GB_BLOCKS) graph_bounds.
__global__ void hist1_misc(const int* __restrict__ col, int* __restrict__ ghistT, int E,
                           const float* __restrict__ convW, uint4* __restrict__ wfrag,
                           __half* __restrict__ ht1, __half* __restrict__ ht2,
                           const int* __restrict__ batch, int* __restrict__ start) {
    __shared__ int lh[NBUK];
    int tid = threadIdx.x, b = blockIdx.x;
    if (b < HGRID) {
        for (int i = tid; i < NBUK; i += 256) lh[i] = 0;
        __syncthreads();
        for (int e = b * 256 + tid; e < E; e += HGRID * 256) atomicAdd(&lh[col[e] >> 7], 1);
        __syncthreads();
        for (int i = tid; i < NBUK; i += 256) ghistT[i * 256 + b] = lh[i];
    } else if (b < HGRID + 4) {
        // prepack conv weights into MFMA B-fragment order (fp16)
        int layer = b - HGRID;
        const float* W = convW + (size_t)layer * HD * HD;
        uint4* out = wfrag + (size_t)layer * 512;
        for (int s = tid; s < 512; s += 256) {
            int jt = s >> 7, ks = (s >> 6) & 1, l = s & 63;
            int j = jt * 16 + (l & 15);
            int k0 = ks * 32 + (l >> 4) * 8;
            __align__(16) __half hh[8];
            #pragma unroll
            for (int i = 0; i < 8; ++i) hh[i] = __float2half_rn(W[(size_t)(k0 + i) * HD + j]);
            out[s] = *reinterpret_cast<const uint4*>(hh);
        }
    } else if (b == HGRID + 4) {
        if (tid < HD) ht1[(size_t)N_NODES * HD + tid] = __float2half_rn(0.f);
        else if (tid < 2 * HD) ht2[(size_t)N_NODES * HD + (tid - HD)] = __float2half_rn(0.f);
    } else {
        int i = (b - HGRID - 5) * 256 + tid;
        if (i < N_NODES) {
            int bb = batch[i];
            if (i == 0) {
                for (int g = 0; g <= bb; ++g) start[g] = 0;
            } else {
                int pb = batch[i - 1];
                if (pb != bb) for (int g = pb + 1; g <= bb; ++g) start[g] = i;
            }
            if (i == N_NODES - 1) {
                for (int g = bb + 1; g <= N_GRAPHS; ++g) start[g] = N_NODES;
            }
        }
    }
}

// per-bucket exclusive scan over the 256 block counts; tot[k] = bucket total
__global__ void hist_colscan(int* __restrict__ ghistT, int* __restrict__ tot) {
    __shared__ int wsum[4];
    int k = blockIdx.x, tid = threadIdx.x;
    int v = ghistT[k * 256 + tid];
    int incl = v;
    int lane = tid & 63;
    #pragma unroll
    for (int off = 1; off < 64; off <<= 1) {
        int t = __shfl_up(incl, (unsigned)off, 64);
        if (lane >= off) incl += t;
    }
    if (lane == 63) wsum[tid >> 6] = incl;
    __syncthreads();
    int woff = 0;
    for (int w = 0; w < (tid >> 6); ++w) woff += wsum[w];
    ghistT[k * 256 + tid] = woff + incl - v;  // exclusive
    if (tid == 255) tot[k] = woff + incl;
}

// generic 1-block exclusive scan (up to 1024 elems)
__global__ void scan1(const int* __restrict__ in, int* __restrict__ out,
                      int* __restrict__ bsums, int n) {
    __shared__ int wsum[4];
    int tid = threadIdx.x;
    int base = blockIdx.x * 1024 + tid * 4;
    int v0 = (base + 0 < n) ? in[base + 0] : 0;
    int v1 = (base + 1 < n) ? in[base + 1] : 0;
    int v2 = (base + 2 < n) ? in[base + 2] : 0;
    int v3 = (base + 3 < n) ? in[base + 3] : 0;
    int tsum = v0 + v1 + v2 + v3;
    int incl = tsum;
    int lane = tid & 63;
    #pragma unroll
    for (int off = 1; off < 64; off <<= 1) {
        int t = __shfl_up(incl, (unsigned)off, 64);
        if (lane >= off) incl += t;
    }
    if (lane == 63) wsum[tid >> 6] = incl;
    __syncthreads();
    int woff = 0;
    for (int w = 0; w < (tid >> 6); ++w) woff += wsum[w];
    int run = woff + incl - tsum;
    if (base + 0 < n) out[base + 0] = run; run += v0;
    if (base + 1 < n) out[base + 1] = run; run += v1;
    if (base + 2 < n) out[base + 2] = run; run += v2;
    if (base + 3 < n) out[base + 3] = run;
    if (tid == 255) bsums[blockIdx.x] = woff + incl;
}

// scatter edges into bucket segments (LDS cursors, packed row|local<<25)
__global__ void scatter_buckets(const int* __restrict__ row, const int* __restrict__ col,
                                const int* __restrict__ ghistT, const int* __restrict__ boff,
                                unsigned* __restrict__ bke, int E) {
    __shared__ int cur[NBUK];
    int tid = threadIdx.x, b = blockIdx.x;
    for (int i = tid; i < NBUK; i += 256) cur[i] = ghistT[i * 256 + b] + boff[i];
    __syncthreads();
    for (int e = b * 256 + tid; e < E; e += HGRID * 256) {
        int c = col[e];
        int pos = atomicAdd(&cur[c >> 7], 1);  // LDS atomic
        bke[pos] = (unsigned)row[e] | ((unsigned)(c & 127) << 25);
    }
}

// per-bucket LDS count -> cnt16, dis, and bucket padded total btot[k]
__global__ void bucket_count(const unsigned* __restrict__ bke, const int* __restrict__ boff,
                             int* __restrict__ cnt16, float* __restrict__ dis,
                             int* __restrict__ btot, int E) {
    __shared__ int lc[128];
    __shared__ int red[2];
    int k = blockIdx.x, tid = threadIdx.x;
    if (tid < 128) lc[tid] = 0;
    __syncthreads();
    int s = boff[k];
    int t = (k == NBUK - 1) ? E : boff[k + 1];
    for (int i = s + tid; i < t; i += 256) atomicAdd(&lc[bke[i] >> 25], 1);  // LDS atomic
    __syncthreads();
    int c16 = 0;
    if (tid < 128) {
        int node = k * 128 + tid;
        if (node < N_NODES) {
            int c = lc[tid];
            c16 = (c + 15) & ~15;
            cnt16[node] = c16;
            dis[node] = rsqrtf((float)(c + 1));
        }
        // wave-reduce c16 over the 2 active waves
        int sum = c16;
        #pragma unroll
        for (int off = 1; off < 64; off <<= 1) sum += __shfl_xor(sum, off, 64);
        if ((tid & 63) == 0) red[tid >> 6] = sum;
    }
    __syncthreads();
    if (tid == 0) btot[k] = red[0] + red[1];
}

// fused: per-bucket CSR fill (+offs via LDS scan, +pads)  AND  encoder sections
__global__ void fill_enc(const unsigned* __restrict__ bke, const int* __restrict__ boff,
                         const int* __restrict__ bbase, const int* __restrict__ cnt16,
                         int* __restrict__ offs, int* __restrict__ srcs, int E,
                         const float* __restrict__ x, const float* __restrict__ encW,
                         const float* __restrict__ encb, const float* __restrict__ dis,
                         __half* __restrict__ ht) {
    int tid = threadIdx.x;
    int b = blockIdx.x;
    if (b < NBUK) {
        __shared__ int offsL[128];
        __shared__ int cur[128];
        __shared__ int wtot[2];
        int k = b;
        int v = 0, incl = 0;
        if (tid < 128) {
            int node = k * 128 + tid;
            v = (node < N_NODES) ? cnt16[node] : 0;
            incl = v;
            int lane = tid & 63;
            #pragma unroll
            for (int off = 1; off < 64; off <<= 1) {
                int t = __shfl_up(incl, (unsigned)off, 64);
                if (lane >= off) incl += t;
            }
            if (lane == 63) wtot[tid >> 6] = incl;
        }
        __syncthreads();
        if (tid < 128) {
            int w0 = (tid >= 64) ? wtot[0] : 0;
            int node = k * 128 + tid;
            int o = bbase[k] + w0 + incl - v;
            offsL[tid] = o;
            cur[tid] = 0;
            if (node < N_NODES) offs[node] = o;
        }
        __syncthreads();
        int s = boff[k];
        int t = (k == NBUK - 1) ? E : boff[k + 1];
        for (int i = s + tid; i < t; i += 256) {
            unsigned u = bke[i];
            int l = u >> 25;
            int r = atomicAdd(&cur[l], 1);  // LDS atomic
            srcs[offsL[l] + r] = (int)(u & 0x01FFFFFFu);
        }
        __syncthreads();
        if (tid < 128) {
            int node = k * 128 + tid;
            if (node < N_NODES) {
                int c = cur[tid];
                int c16 = (c + 15) & ~15;
                int base = offsL[tid];
                for (int p = base + c; p < base + c16; ++p) srcs[p] = N_NODES;  // pad
            }
        }
    } else {
        // encoder: ht = fp16( dis * relu(x @ encW + encb) )
        __shared__ float Ws[F_INN * HD];
        __shared__ float bs[HD];
        __shared__ float xs[16 * F_INN];
        for (int i = tid; i < F_INN * HD; i += 256) Ws[i] = encW[i];
        if (tid < HD) bs[tid] = encb[tid];
        int n0 = (b - NBUK) * 16;
        for (int i = tid; i < 16 * F_INN; i += 256) {
            int nn = n0 + i / F_INN;
            xs[i] = (nn < N_NODES) ? x[(size_t)nn * F_INN + (i % F_INN)] : 0.f;
        }
        __syncthreads();
        #pragma unroll
        for (int it = 0; it < 4; ++it) {
            int l = it * 4 + (tid >> 6);
            int j = tid & 63;
            int nn = n0 + l;
            if (nn < N_NODES) {
                float a = bs[j];
                #pragma unroll
                for (int k = 0; k < F_INN; ++k) a = fmaf(xs[l * F_INN + k], Ws[k * HD + j], a);
                ht[(size_t)nn * HD + j] = __float2half_rn(dis[nn] * fmaxf(a, 0.f));
            }
        }
    }
}

// ---------------- GCN layer ----------------

__device__ __forceinline__ float4 cvtrow(uint2 u) {
    float2 a = __half22float2(*reinterpret_cast<const __half2*>(&u.x));
    float2 b = __half22float2(*reinterpret_cast<const __half2*>(&u.y));
    return make_float4(a.x, a.y, b.x, b.y);
}

#define ROW16(src) (*reinterpret_cast<const uint2*>(&ht[(size_t)(src) * HD + fh]))
#define H2(u) (*reinterpret_cast<const __half2*>(&(u)))
// 4-row fp16 tree -> fp32 accumulate
#define ACC4T(r0, r1, r2, r3) { \
    __half2 ax = __hadd2(__hadd2(H2(r0.x), H2(r1.x)), __hadd2(H2(r2.x), H2(r3.x))); \
    __half2 ay = __hadd2(__hadd2(H2(r0.y), H2(r1.y)), __hadd2(H2(r2.y), H2(r3.y))); \
    float2 fx = __half22float2(ax); \
    float2 fy = __half22float2(ay); \
    acc.x += fx.x; acc.y += fx.y; acc.z += fy.x; acc.w += fy.y; }

// Bucketed GCN layer: block owns 64 dests; quarter-wave walks 4 dests' padded CSR
// slots (16/group). Self rows pre-staged into aggS (latency hidden under gather);
// flush adds acc to the staged self row in fp32, stores fp16. Block-coop MFMA.
__global__ void layer_kernel(const __half* __restrict__ ht,
                             const int* __restrict__ offs, const int* __restrict__ cnt16,
                             const int4* __restrict__ srcs4,
                             const float* __restrict__ dis,
                             const uint4* __restrict__ wfragL, const float* __restrict__ bias,
                             __half* __restrict__ hout, int scaleOut) {
    __shared__ uint4 WfS[512];        // 8KB B-fragments
    __shared__ __half aggS[64 * 72];  // 64 agg rows, stride 72 halfs
    __shared__ int offsS[64];
    __shared__ int cntS[64];
    __shared__ float disS[64];
    int tid = threadIdx.x;
    int b = blockIdx.x;
    WfS[tid] = wfragL[tid];
    WfS[tid + 256] = wfragL[tid + 256];
    if (tid < 64) {
        int d = b * 64 + tid;
        if (d < N_NODES) {
            offsS[tid] = offs[d];
            cntS[tid] = cnt16[d];
            disS[tid] = dis[d];
        } else {
            offsS[tid] = offs[N_NODES - 1] + cnt16[N_NODES - 1];
            cntS[tid] = 0;
            disS[tid] = 0.f;
        }
    }
    __syncthreads();

    int wave = tid >> 6;
    int lane = tid & 63;
    int q = lane >> 4;
    int fh = (lane & 15) * 4;

    int l0 = wave * 16 + q * 4;
    // pre-stage self rows into this quarter's aggS rows (global latency hidden)
    {
        int nbase = b * 64 + l0;
        *reinterpret_cast<uint2*>(&aggS[(l0 + 0) * 72 + fh]) = ROW16(min(nbase + 0, N_NODES));
        *reinterpret_cast<uint2*>(&aggS[(l0 + 1) * 72 + fh]) = ROW16(min(nbase + 1, N_NODES));
        *reinterpret_cast<uint2*>(&aggS[(l0 + 2) * 72 + fh]) = ROW16(min(nbase + 2, N_NODES));
        *reinterpret_cast<uint2*>(&aggS[(l0 + 3) * 72 + fh]) = ROW16(min(nbase + 3, N_NODES));
    }
    int s = offsS[l0];
    int e = offsS[l0 + 3] + cntS[l0 + 3];
    int dcur = l0;
    int nb = offsS[l0] + cntS[l0];
    float4 acc = {0.f, 0.f, 0.f, 0.f};

    // flush: add staged self row (fp32), store fp16 agg row, reset acc
    auto flush = [&](int d) {
        uint2 sv = *reinterpret_cast<uint2*>(&aggS[d * 72 + fh]);
        float4 sf = cvtrow(sv);
        acc.x += sf.x; acc.y += sf.y; acc.z += sf.z; acc.w += sf.w;
        __half2 h0 = __floats2half2_rn(acc.x, acc.y);
        __half2 h1 = __floats2half2_rn(acc.z, acc.w);
        uint2 w;
        w.x = *(unsigned*)&h0;
        w.y = *(unsigned*)&h1;
        *reinterpret_cast<uint2*>(&aggS[d * 72 + fh]) = w;
        acc = make_float4(0.f, 0.f, 0.f, 0.f);
    };

    for (int p = s; p < e; p += 16) {
        while (p >= nb) {
            flush(dcur);
            ++dcur;
            nb = offsS[dcur] + cntS[dcur];
        }
        int base = p >> 2;
        int4 e0 = srcs4[base + 0];
        int4 e1 = srcs4[base + 1];
        int4 e2 = srcs4[base + 2];
        int4 e3 = srcs4[base + 3];
        uint2 r0 = ROW16(e0.x), r1 = ROW16(e0.y), r2 = ROW16(e0.z), r3 = ROW16(e0.w);
        uint2 r4 = ROW16(e1.x), r5 = ROW16(e1.y), r6 = ROW16(e1.z), r7 = ROW16(e1.w);
        uint2 r8 = ROW16(e2.x), r9 = ROW16(e2.y), r10 = ROW16(e2.z), r11 = ROW16(e2.w);
        uint2 r12 = ROW16(e3.x), r13 = ROW16(e3.y), r14 = ROW16(e3.z), r15 = ROW16(e3.w);
        ACC4T(r0, r1, r2, r3);
        ACC4T(r4, r5, r6, r7);
        ACC4T(r8, r9, r10, r11);
        ACC4T(r12, r13, r14, r15);
    }
    while (dcur <= l0 + 3) {
        flush(dcur);
        ++dcur;
    }
    __syncthreads();

    f32x4 c0 = {0.f, 0.f, 0.f, 0.f}, c1 = c0, c2 = c0, c3 = c0;
    #pragma unroll
    for (int ks = 0; ks < 2; ++ks) {
        f16x8 bf = *reinterpret_cast<const f16x8*>(&WfS[(wave * 2 + ks) * 64 + lane]);
        f16x8 a0 = *reinterpret_cast<const f16x8*>(&aggS[(0 * 16 + (lane & 15)) * 72 + ks * 32 + (lane >> 4) * 8]);
        c0 = __builtin_amdgcn_mfma_f32_16x16x32_f16(a0, bf, c0, 0, 0, 0);
        f16x8 a1 = *reinterpret_cast<const f16x8*>(&aggS[(1 * 16 + (lane & 15)) * 72 + ks * 32 + (lane >> 4) * 8]);
        c1 = __builtin_amdgcn_mfma_f32_16x16x32_f16(a1, bf, c1, 0, 0, 0);
        f16x8 a2 = *reinterpret_cast<const f16x8*>(&aggS[(2 * 16 + (lane & 15)) * 72 + ks * 32 + (lane >> 4) * 8]);
        c2 = __builtin_amdgcn_mfma_f32_16x16x32_f16(a2, bf, c2, 0, 0, 0);
        f16x8 a3 = *reinterpret_cast<const f16x8*>(&aggS[(3 * 16 + (lane & 15)) * 72 + ks * 32 + (lane >> 4) * 8]);
        c3 = __builtin_amdgcn_mfma_f32_16x16x32_f16(a3, bf, c3, 0, 0, 0);
    }
    int j = wave * 16 + (lane & 15);
    float bj = bias[j];
    #pragma unroll
    for (int nt = 0; nt < 4; ++nt) {
        f32x4 c = (nt == 0) ? c0 : (nt == 1) ? c1 : (nt == 2) ? c2 : c3;
        #pragma unroll
        for (int i = 0; i < 4; ++i) {
            int rl = nt * 16 + (lane >> 4) * 4 + i;
            int node = b * 64 + rl;
            if (node < N_NODES) {
                float dn = disS[rl];
                float o = fmaxf(fmaf(dn, c[i], bj), 0.f);
                if (scaleOut) o *= dn;
                hout[(size_t)node * HD + j] = __float2half_rn(o);
            }
        }
    }
}

// fused heads: sections [0,NH_BLOCKS) node head; rest pool quarters
__global__ void heads_kernel(const __half* __restrict__ h, const float* __restrict__ W,
                             const float* __restrict__ bb, float* __restrict__ out,
                             const int* __restrict__ start, float* __restrict__ gpart) {
    int tid = threadIdx.x;
    int b = blockIdx.x;
    if (b < NH_BLOCKS) {
        __shared__ float Ws[HD * NT];
        __shared__ float bs[NT];
        __shared__ float hs[32 * 65];
        for (int i = tid; i < HD * NT; i += 256) Ws[i] = W[i];
        if (tid < NT) bs[tid] = bb[tid];
        int n0 = b * 32;
        const unsigned* hrow = reinterpret_cast<const unsigned*>(&h[(size_t)n0 * HD]);
        for (int i = tid; i < 32 * HD / 2; i += 256) {
            unsigned u = hrow[i];
            float2 f = __half22float2(*reinterpret_cast<const __half2*>(&u));
            int el = i * 2;
            int row = el >> 6, colc = el & 63;
            hs[row * 65 + colc] = f.x;
            hs[row * 65 + colc + 1] = f.y;
        }
        __syncthreads();
        int l = tid >> 3, t = tid & 7;
        int nn = n0 + l;
        if (nn < N_NODES && t < NT) {
            float a = bs[t];
            #pragma unroll
            for (int k = 0; k < HD; ++k) a = fmaf(hs[l * 65 + k], Ws[k * NT + t], a);
            out[(size_t)nn * NT + t] = a;
        }
    } else {
        __shared__ float red[4][HD];
        int pb = b - NH_BLOCKS;
        int g = pb >> 2, q = pb & 3;
        int s0 = start[g], e0 = start[g + 1];
        int len = e0 - s0;
        int qs = s0 + (len * q) / 4;
        int qe = s0 + (len * (q + 1)) / 4;
        int wave = tid >> 6, lane = tid & 63;
        float acc = 0.f;
        for (int r = qs + wave; r < qe; r += 4) acc += __half2float(h[(size_t)r * HD + lane]);
        red[wave][lane] = acc;
        __syncthreads();
        if (wave == 0)
            gpart[(size_t)pb * HD + lane] =
                red[0][lane] + red[1][lane] + red[2][lane] + red[3][lane];
    }
}

__global__ void global_head(const float* __restrict__ gpart, const int* __restrict__ start,
                            const float* __restrict__ g1W, const float* __restrict__ g1b,
                            const float* __restrict__ g2W, const float* __restrict__ g2b,
                            float* __restrict__ out) {
    __shared__ float rS[HD];
    int g = blockIdx.x;
    int j = threadIdx.x;  // 64
    int cnt = start[g + 1] - start[g];
    float inv = 1.f / fmaxf((float)cnt, 1.f);
    rS[j] = (gpart[(size_t)(4 * g + 0) * HD + j] + gpart[(size_t)(4 * g + 1) * HD + j] +
             gpart[(size_t)(4 * g + 2) * HD + j] + gpart[(size_t)(4 * g + 3) * HD + j]) * inv;
    __syncthreads();
    float a = g1b[j];
    #pragma unroll
    for (int k = 0; k < HD; ++k) a = fmaf(rS[k], g1W[k * HD + j], a);
    a = fmaxf(a, 0.f);
    float o0 = a * g2W[j * GT + 0];
    float o1 = a * g2W[j * GT + 1];
    float o2 = a * g2W[j * GT + 2];
    float o3 = a * g2W[j * GT + 3];
    #pragma unroll
    for (int off = 1; off < 64; off <<= 1) {
        o0 += __shfl_xor(o0, off, 64);
        o1 += __shfl_xor(o1, off, 64);
        o2 += __shfl_xor(o2, off, 64);
        o3 += __shfl_xor(o3, off, 64);
    }
    if (j == 0) {
        out[g * GT + 0] = o0 + g2b[0];
        out[g * GT + 1] = o1 + g2b[1];
        out[g * GT + 2] = o2 + g2b[2];
        out[g * GT + 3] = o3 + g2b[3];
    }
}

// ---------------- launch ----------------

extern "C" void kernel_launch(void* const* d_in, const int* in_sizes, int n_in,
                              void* d_out, int out_size, void* d_ws, size_t ws_size,
                              hipStream_t stream) {
    const float* x    = (const float*)d_in[0];
    const int*   ei   = (const int*)d_in[1];
    const int*   batch= (const int*)d_in[2];
    const float* encW = (const float*)d_in[3];
    const float* encb = (const float*)d_in[4];
    const float* convW= (const float*)d_in[5];
    const float* convb= (const float*)d_in[6];
    const float* nodeW= (const float*)d_in[7];
    const float* nodeb= (const float*)d_in[8];
    const float* g1W  = (const float*)d_in[9];
    const float* g1b  = (const float*)d_in[10];
    const float* g2W  = (const float*)d_in[11];
    const float* g2b  = (const float*)d_in[12];
    float* out = (float*)d_out;

    const int N = N_NODES, E = N_EDGES;

    char* ws = (char*)d_ws;
    size_t off = 0;
    auto alloc = [&](size_t bytes) -> void* {
        void* p = ws + off;
        off += (bytes + 255) & ~(size_t)255;
        return p;
    };
    // all buffers fully written before read — no memset needed
    int*    ghistT = (int*)alloc((size_t)NBUK * 256 * 4);
    int*    tot    = (int*)alloc((size_t)NBUK * 4);
    int*    boff   = (int*)alloc((size_t)NBUK * 4);
    int*    btot   = (int*)alloc((size_t)NBUK * 4);
    int*    bbase  = (int*)alloc((size_t)NBUK * 4);
    unsigned* bke  = (unsigned*)alloc((size_t)E * 4);
    int*    offs   = (int*)alloc((size_t)N * 4);
    int*    cnt16  = (int*)alloc((size_t)N * 4);
    float*  dis    = (float*)alloc((size_t)N * 4);
    int*    bsums  = (int*)alloc(256 * 4);
    int*    start  = (int*)alloc((size_t)(N_GRAPHS + 1) * 4);
    float*  gpart  = (float*)alloc((size_t)N_GRAPHS * 4 * HD * 4);
    uint4*  wfrag  = (uint4*)alloc((size_t)NLAYERS * 512 * 16);
    int*    srcs   = (int*)alloc((size_t)RECS_CAP * 4);
    __half* ht1    = (__half*)alloc((size_t)(N + 1) * HD * 2);  // +1 pad row
    __half* ht2    = (__half*)alloc((size_t)(N + 1) * HD * 2);

    // fused build + misc (hist, prepack, pad rows, graph bounds)
    hist1_misc<<<HGRID + 5 + GB_BLOCKS, 256, 0, stream>>>(ei + E, ghistT, E, convW, wfrag,
                                                          ht1, ht2, batch, start);
    hist_colscan<<<NBUK, 256, 0, stream>>>(ghistT, tot);
    scan1<<<1, 256, 0, stream>>>(tot, boff, bsums, NBUK);
    scatter_buckets<<<HGRID, 256, 0, stream>>>(ei, ei + E, ghistT, boff, bke, E);
    bucket_count<<<NBUK, 256, 0, stream>>>(bke, boff, cnt16, dis, btot, E);
    scan1<<<1, 256, 0, stream>>>(btot, bbase, bsums, NBUK);
    fill_enc<<<NBUK + ENC_BLOCKS, 256, 0, stream>>>(bke, boff, bbase, cnt16, offs, srcs, E,
                                                    x, encW, encb, dis, ht1);

    __half* hin = ht1;
    __half* hot = ht2;
    for (int i = 0; i < NLAYERS; ++i) {
        layer_kernel<<<NBLK, 256, 0, stream>>>(hin, offs, cnt16, (const int4*)srcs, dis,
                                               wfrag + (size_t)i * 512,
                                               convb + (size_t)i * HD,
                                               hot, (i < NLAYERS - 1) ? 1 : 0);
        __half* t = hin; hin = hot; hot = t;
    }

    heads_kernel<<<NH_BLOCKS + N_GRAPHS * 4, 256, 0, stream>>>(hin, nodeW, nodeb, out,
                                                               start, gpart);
    global_head<<<N_GRAPHS, 64, 0, stream>>>(gpart, start, g1W, g1b, g2W, g2b, out + (size_t)N * NT);
}